// Round 1
// baseline (2748.394 us; speedup 1.0000x reference)
//
#include <hip/hip_runtime.h>
#include <cstddef>

#define NEGV (-1e12f)

// Sizes (fixed by the problem): B=64, N=256, H=512, HEADS=8, DK=64, NBINS=3

// ---------------------------------------------------------------------------
// Wcat[o][i*512+c] = sum_e Ws1[o, i*512+e] * Wa[i, e, c]
// (folds the per-bin output projection Wa into the first MLP layer Ws1)
__global__ __launch_bounds__(256) void msa_wcat(const float* __restrict__ Ws1,
                                                const float* __restrict__ Wa,
                                                float* __restrict__ Wcat) {
  int t = blockIdx.x * 256 + threadIdx.x;   // 3 * 128 * 512 = 196608 threads
  int c = t & 511;
  int og = (t >> 9) & 127;                  // o-group of 4
  int i = t >> 16;
  const float* wap = Wa + ((size_t)i << 18) + c;
  const float* w0 = Ws1 + (size_t)(og * 4 + 0) * 1536 + i * 512;
  const float* w1 = w0 + 1536;
  const float* w2 = w0 + 3072;
  const float* w3 = w0 + 4608;
  float a0 = 0.f, a1 = 0.f, a2 = 0.f, a3 = 0.f;
  for (int e = 0; e < 512; ++e) {
    float wv = wap[(size_t)e << 9];
    a0 += w0[e] * wv; a1 += w1[e] * wv; a2 += w2[e] * wv; a3 += w3[e] * wv;
  }
  size_t base = (size_t)(og * 4) * 1536 + i * 512 + c;
  Wcat[base] = a0; Wcat[base + 1536] = a1;
  Wcat[base + 3072] = a2; Wcat[base + 4608] = a3;
}

// bcomb[o] = bs1[o] + sum_cidx Ws1[o, cidx] * ba_flat[cidx]
__global__ __launch_bounds__(256) void msa_bcomb(const float* __restrict__ Ws1,
                                                 const float* __restrict__ ba,
                                                 const float* __restrict__ bs1,
                                                 float* __restrict__ bcomb) {
  int o = blockIdx.x * 256 + threadIdx.x;   // grid 2
  float acc = bs1[o];
  for (int cidx = 0; cidx < 1536; ++cidx)
    acc += Ws1[(size_t)o * 1536 + cidx] * ba[cidx];
  bcomb[o] = acc;
}

// ---------------------------------------------------------------------------
// Generic fp32 NT GEMM:  C[m,n] = sum_k A[m,k]*W[n,k] + bias[n]  (+silu)(+resid)
// 128x128 tile, 8x8 micro-tile, 256 threads.
template <int ACT, int RES>
__global__ __launch_bounds__(256) void msa_gemm_nt(const float* __restrict__ A, int lda,
                                                   const float* __restrict__ W, int ldw,
                                                   const float* __restrict__ bias,
                                                   const float* __restrict__ resid,
                                                   float* __restrict__ C, int ldc,
                                                   int Kdim) {
  __shared__ float As[8][132];
  __shared__ float Bs[8][132];
  const int tid = threadIdx.x;
  const int m0 = blockIdx.x * 128, n0 = blockIdx.y * 128;
  const int lrow = tid >> 1, lk4 = (tid & 1) << 2;
  const int tx = tid & 15, ty = tid >> 4;
  float acc[8][8];
#pragma unroll
  for (int i = 0; i < 8; ++i)
#pragma unroll
    for (int j = 0; j < 8; ++j) acc[i][j] = 0.f;
  const float* Ald = A + (size_t)(m0 + lrow) * lda + lk4;
  const float* Wld = W + (size_t)(n0 + lrow) * ldw + lk4;
  for (int kt = 0; kt < Kdim; kt += 8) {
    float4 a4 = *(const float4*)(Ald + kt);
    float4 b4 = *(const float4*)(Wld + kt);
    __syncthreads();
    As[lk4 + 0][lrow] = a4.x; As[lk4 + 1][lrow] = a4.y;
    As[lk4 + 2][lrow] = a4.z; As[lk4 + 3][lrow] = a4.w;
    Bs[lk4 + 0][lrow] = b4.x; Bs[lk4 + 1][lrow] = b4.y;
    Bs[lk4 + 2][lrow] = b4.z; Bs[lk4 + 3][lrow] = b4.w;
    __syncthreads();
#pragma unroll
    for (int k = 0; k < 8; ++k) {
      float am[8], bn[8];
      *(float4*)&am[0] = *(const float4*)&As[k][ty * 4];
      *(float4*)&am[4] = *(const float4*)&As[k][ty * 4 + 64];
      *(float4*)&bn[0] = *(const float4*)&Bs[k][tx * 4];
      *(float4*)&bn[4] = *(const float4*)&Bs[k][tx * 4 + 64];
#pragma unroll
      for (int i = 0; i < 8; ++i)
#pragma unroll
        for (int j = 0; j < 8; ++j) acc[i][j] += am[i] * bn[j];
    }
  }
#pragma unroll
  for (int i = 0; i < 8; ++i) {
    const int m = m0 + ty * 4 + (i & 3) + ((i >> 2) << 6);
#pragma unroll
    for (int jh = 0; jh < 2; ++jh) {
      const int n = n0 + tx * 4 + (jh << 6);
      float vv[4];
#pragma unroll
      for (int j = 0; j < 4; ++j) {
        float val = acc[i][jh * 4 + j] + bias[n + j];
        if (ACT == 1) val = val / (1.f + __expf(-val));   // silu
        if (RES == 1) val += resid[(size_t)m * ldc + n + j];
        vv[j] = val;
      }
      *(float4*)&C[(size_t)m * ldc + n] = make_float4(vv[0], vv[1], vv[2], vv[3]);
    }
  }
}

// ---------------------------------------------------------------------------
// Attention scores + 3-bin masked softmax. One block per (b,h), 512 threads.
// K tile in LDS; each wave handles 4 q-rows at a time; lane owns cols
// {lane, lane+64, lane+128, lane+192}. Per-lane d-rotation makes the b128
// LDS reads bank-uniform. Writes attn probabilities (output 1) directly.
__global__ __launch_bounds__(512) void msa_attn(const float* __restrict__ qg,
                                                const float* __restrict__ kg,
                                                const float* __restrict__ dist,
                                                const float* __restrict__ dist_bar,
                                                const float* __restrict__ maskg,
                                                float* __restrict__ attn_out) {
  const int bh = blockIdx.x;
  const int b = bh >> 3, h = bh & 7;
  __shared__ float Klds[256 * 64];   // 64 KiB
  __shared__ float qbuf[32 * 64];    // 8 KiB (4 rows per wave, 8 waves)
  const int tid = threadIdx.x;
  const int w = tid >> 6, lane = tid & 63;
  // stage K for this (b,h)
  for (int i = 0; i < 8; ++i) {
    int s = tid + i * 512;
    int j = s >> 4, d4 = (s & 15) << 2;
    *(float4*)&Klds[j * 64 + d4] =
        *(const float4*)&kg[((size_t)(b * 256 + j)) * 512 + h * 64 + d4];
  }
  const float cut0 = dist_bar[b * 3 + 0];
  const float cut1 = dist_bar[b * 3 + 1];
  const float cut2 = dist_bar[b * 3 + 2];
  __syncthreads();
  const int rot = (lane & 15) << 2;
  for (int rr = 0; rr < 8; ++rr) {
    // stage 4 q-rows per wave
    for (int i = 0; i < 4; ++i) {
      int s = tid + i * 512;
      int wrow = s >> 6, d = s & 63;
      int grow = (wrow >> 2) * 32 + rr * 4 + (wrow & 3);
      qbuf[wrow * 64 + d] = qg[((size_t)(b * 256 + grow)) * 512 + h * 64 + d];
    }
    __syncthreads();
    float s_[4][4];
#pragma unroll
    for (int r = 0; r < 4; ++r)
#pragma unroll
      for (int c = 0; c < 4; ++c) s_[r][c] = 0.f;
#pragma unroll
    for (int d4i = 0; d4i < 16; ++d4i) {
      int dd = (d4i * 4 + rot) & 63;
      float4 k4[4];
#pragma unroll
      for (int c = 0; c < 4; ++c)
        k4[c] = *(const float4*)&Klds[(lane + 64 * c) * 64 + dd];
#pragma unroll
      for (int r = 0; r < 4; ++r) {
        float4 q4 = *(const float4*)&qbuf[(w * 4 + r) * 64 + dd];
#pragma unroll
        for (int c = 0; c < 4; ++c)
          s_[r][c] += q4.x * k4[c].x + q4.y * k4[c].y +
                      q4.z * k4[c].z + q4.w * k4[c].w;
      }
    }
    const int row0 = w * 32 + rr * 4;
#pragma unroll
    for (int r = 0; r < 4; ++r) {
      const int row = row0 + r;
      float base[4], dv[4];
#pragma unroll
      for (int c = 0; c < 4; ++c) {
        int j = lane + 64 * c;
        float mv = maskg[(size_t)b * 65536 + (size_t)row * 256 + j];
        float sc = s_[r][c] * 0.125f;                 // 1/sqrt(64)
        base[c] = (mv == 0.f) ? NEGV : sc;            // padding mask first
        // new_dist: super row/col always kept -> represent as -1e30 (< any cut)
        dv[c] = (row == 0 || j == 0)
                    ? -1e30f
                    : dist[(size_t)b * 65025 + (size_t)(row - 1) * 255 + (j - 1)];
      }
#pragma unroll
      for (int bin = 0; bin < 3; ++bin) {
        float cut = (bin == 0) ? cut0 : (bin == 1) ? cut1 : cut2;
        float sd[4];
#pragma unroll
        for (int c = 0; c < 4; ++c) sd[c] = (dv[c] < cut) ? base[c] : NEGV;
        float m = fmaxf(fmaxf(sd[0], sd[1]), fmaxf(sd[2], sd[3]));
#pragma unroll
        for (int off = 32; off > 0; off >>= 1) m = fmaxf(m, __shfl_xor(m, off));
        float p[4], sum = 0.f;
#pragma unroll
        for (int c = 0; c < 4; ++c) { p[c] = __expf(sd[c] - m); sum += p[c]; }
#pragma unroll
        for (int off = 32; off > 0; off >>= 1) sum += __shfl_xor(sum, off);
        float inv = 1.f / sum;
        float* op = attn_out + ((size_t)((bin * 64 + b) * 8 + h)) * 65536 +
                    (size_t)row * 256;
#pragma unroll
        for (int c = 0; c < 4; ++c) op[lane + 64 * c] = p[c] * inv;
      }
    }
    __syncthreads();
  }
}

// ---------------------------------------------------------------------------
// PV: per (b,h,bin) GEMM  MO[256,64] = attn[256,256] @ V[256,64]
// 256 threads, 16x4 micro-tile, K-tile 16.
__global__ __launch_bounds__(256) void msa_pv(const float* __restrict__ attn,
                                              const float* __restrict__ vg,
                                              float* __restrict__ mo) {
  const int bh = blockIdx.x, bin = blockIdx.y;
  const int b = bh >> 3, h = bh & 7;
  __shared__ float As[16][260];   // P^T tile: As[k][q]
  __shared__ float Bs[16][64];    // V tile
  const int tid = threadIdx.x;
  const int tx = tid & 15, ty = tid >> 4;
  const float* Ag = attn + ((size_t)((bin * 64 + b) * 8 + h)) * 65536;
  const float* Vg = vg + (size_t)b * 131072 + h * 64;
  float acc[16][4];
#pragma unroll
  for (int i = 0; i < 16; ++i)
#pragma unroll
    for (int j = 0; j < 4; ++j) acc[i][j] = 0.f;
  for (int kt = 0; kt < 256; kt += 16) {
    __syncthreads();
#pragma unroll
    for (int i = 0; i < 4; ++i) {
      int s = tid + i * 256;
      int qr = s >> 2, k4 = (s & 3) << 2;
      float4 a4 = *(const float4*)&Ag[(size_t)qr * 256 + kt + k4];
      As[k4 + 0][qr] = a4.x; As[k4 + 1][qr] = a4.y;
      As[k4 + 2][qr] = a4.z; As[k4 + 3][qr] = a4.w;
    }
    {
      int kk = tid >> 4, d4 = (tid & 15) << 2;
      *(float4*)&Bs[kk][d4] = *(const float4*)&Vg[(size_t)(kt + kk) * 512 + d4];
    }
    __syncthreads();
#pragma unroll
    for (int kk = 0; kk < 16; ++kk) {
      float a[16], bb[4];
      *(float4*)&a[0]  = *(const float4*)&As[kk][ty * 4];
      *(float4*)&a[4]  = *(const float4*)&As[kk][ty * 4 + 64];
      *(float4*)&a[8]  = *(const float4*)&As[kk][ty * 4 + 128];
      *(float4*)&a[12] = *(const float4*)&As[kk][ty * 4 + 192];
      *(float4*)&bb[0] = *(const float4*)&Bs[kk][tx * 4];
#pragma unroll
      for (int i = 0; i < 16; ++i)
#pragma unroll
        for (int j = 0; j < 4; ++j) acc[i][j] += a[i] * bb[j];
    }
  }
#pragma unroll
  for (int i = 0; i < 16; ++i) {
    int q_ = ty * 4 + (i & 3) + ((i >> 2) << 6);
    float* cp = mo + ((size_t)(b * 256 + q_) * 3 + bin) * 512 + h * 64 + tx * 4;
    *(float4*)cp = make_float4(acc[i][0], acc[i][1], acc[i][2], acc[i][3]);
  }
}

// ---------------------------------------------------------------------------
// LayerNorm: one wave per row of 512.
__global__ __launch_bounds__(256) void msa_ln(const float* __restrict__ h2,
                                              const float* __restrict__ gamma,
                                              const float* __restrict__ beta,
                                              float* __restrict__ outp) {
  const int row = blockIdx.x * 4 + (threadIdx.x >> 6);
  const int lane = threadIdx.x & 63;
  const float* hp = h2 + (size_t)row * 512 + lane * 8;
  float4 v0 = *(const float4*)hp;
  float4 v1 = *(const float4*)(hp + 4);
  float s = v0.x + v0.y + v0.z + v0.w + v1.x + v1.y + v1.z + v1.w;
#pragma unroll
  for (int off = 32; off > 0; off >>= 1) s += __shfl_xor(s, off);
  float mu = s * (1.f / 512.f);
  float d[8] = {v0.x - mu, v0.y - mu, v0.z - mu, v0.w - mu,
                v1.x - mu, v1.y - mu, v1.z - mu, v1.w - mu};
  float sq = 0.f;
#pragma unroll
  for (int j = 0; j < 8; ++j) sq += d[j] * d[j];
#pragma unroll
  for (int off = 32; off > 0; off >>= 1) sq += __shfl_xor(sq, off);
  float inv = 1.f / sqrtf(sq * (1.f / 512.f) + 1e-6f);
  const float* gp = gamma + lane * 8;
  const float* bp = beta + lane * 8;
  float* op = outp + (size_t)row * 512 + lane * 8;
#pragma unroll
  for (int j = 0; j < 8; ++j) op[j] = d[j] * inv * gp[j] + bp[j];
}

// ---------------------------------------------------------------------------
extern "C" void kernel_launch(void* const* d_in, const int* in_sizes, int n_in,
                              void* d_out, int out_size, void* d_ws, size_t ws_size,
                              hipStream_t stream) {
  (void)in_sizes; (void)n_in; (void)out_size; (void)ws_size;
  const float* x        = (const float*)d_in[0];
  const float* dist     = (const float*)d_in[1];
  const float* dist_bar = (const float*)d_in[2];
  const float* mask     = (const float*)d_in[3];
  const float* Wq  = (const float*)d_in[4];  const float* bq  = (const float*)d_in[5];
  const float* Wk  = (const float*)d_in[6];  const float* bk  = (const float*)d_in[7];
  const float* Wv  = (const float*)d_in[8];  const float* bv  = (const float*)d_in[9];
  const float* Wa  = (const float*)d_in[10]; const float* ba  = (const float*)d_in[11];
  const float* Ws1 = (const float*)d_in[12]; const float* bs1 = (const float*)d_in[13];
  const float* Ws2 = (const float*)d_in[14]; const float* bs2 = (const float*)d_in[15];
  const float* gamma = (const float*)d_in[16]; const float* beta = (const float*)d_in[17];

  float* ws = (float*)d_ws;
  const size_t SZ = 8388608;          // 16384 * 512
  float* q     = ws;                  // SZ
  float* k     = ws + SZ;             // SZ
  float* v     = ws + 2 * SZ;         // SZ
  float* mo    = ws + 3 * SZ;         // 3*SZ  [B,N,3,512]
  float* Wcat  = ws + 6 * SZ;         // 786432  [512][1536]
  float* bcomb = Wcat + 786432;       // 512
  float* h1 = q;                      // reuse: q dead after attention
  float* h2 = k;                      // reuse: k dead after attention
  float* outp = (float*)d_out;        // [B,N,H] = SZ floats
  float* attn = outp + SZ;            // [3,B,8,256,256]

  msa_wcat<<<768, 256, 0, stream>>>(Ws1, Wa, Wcat);
  msa_bcomb<<<2, 256, 0, stream>>>(Ws1, ba, bs1, bcomb);

  dim3 gproj(128, 4);
  msa_gemm_nt<0, 0><<<gproj, 256, 0, stream>>>(x, 512, Wq, 512, bq, nullptr, q, 512, 512);
  msa_gemm_nt<0, 0><<<gproj, 256, 0, stream>>>(x, 512, Wk, 512, bk, nullptr, k, 512, 512);
  msa_gemm_nt<0, 0><<<gproj, 256, 0, stream>>>(x, 512, Wv, 512, bv, nullptr, v, 512, 512);

  msa_attn<<<512, 512, 0, stream>>>(q, k, dist, dist_bar, mask, attn);
  msa_pv<<<dim3(512, 3), 256, 0, stream>>>(attn, v, mo);

  // h1 = silu(mo @ Wcat^T + bcomb)
  msa_gemm_nt<1, 0><<<gproj, 256, 0, stream>>>(mo, 1536, Wcat, 1536, bcomb, nullptr,
                                               h1, 512, 1536);
  // h2 = h1 @ Ws2^T + bs2 + x
  msa_gemm_nt<0, 1><<<gproj, 256, 0, stream>>>(h1, 512, Ws2, 512, bs2, x, h2, 512, 512);

  msa_ln<<<4096, 256, 0, stream>>>(h2, gamma, beta, outp);
}

// Round 2
// 1241.794 us; speedup vs baseline: 2.2132x; 2.2132x over previous
//
#include <hip/hip_runtime.h>
#include <cstddef>

#define NEGV (-1e12f)

// Sizes (fixed): B=64, N=256, H=512, HEADS=8, DK=64, NBINS=3

// ---------------------------------------------------------------------------
// Wcat[o][i*512+c] = sum_e Ws1[o, i*512+e] * Wa[i, e, c]
__global__ __launch_bounds__(256) void msa_wcat(const float* __restrict__ Ws1,
                                                const float* __restrict__ Wa,
                                                float* __restrict__ Wcat) {
  int t = blockIdx.x * 256 + threadIdx.x;
  int c = t & 511;
  int og = (t >> 9) & 127;
  int i = t >> 16;
  const float* wap = Wa + ((size_t)i << 18) + c;
  const float* w0 = Ws1 + (size_t)(og * 4 + 0) * 1536 + i * 512;
  const float* w1 = w0 + 1536;
  const float* w2 = w0 + 3072;
  const float* w3 = w0 + 4608;
  float a0 = 0.f, a1 = 0.f, a2 = 0.f, a3 = 0.f;
  for (int e = 0; e < 512; ++e) {
    float wv = wap[(size_t)e << 9];
    a0 += w0[e] * wv; a1 += w1[e] * wv; a2 += w2[e] * wv; a3 += w3[e] * wv;
  }
  size_t base = (size_t)(og * 4) * 1536 + i * 512 + c;
  Wcat[base] = a0; Wcat[base + 1536] = a1;
  Wcat[base + 3072] = a2; Wcat[base + 4608] = a3;
}

__global__ __launch_bounds__(256) void msa_bcomb(const float* __restrict__ Ws1,
                                                 const float* __restrict__ ba,
                                                 const float* __restrict__ bs1,
                                                 float* __restrict__ bcomb) {
  int o = blockIdx.x * 256 + threadIdx.x;
  float acc = bs1[o];
  for (int cidx = 0; cidx < 1536; ++cidx)
    acc += Ws1[(size_t)o * 1536 + cidx] * ba[cidx];
  bcomb[o] = acc;
}

// ---------------------------------------------------------------------------
// Generic fp32 NT GEMM (unchanged from round 1)
template <int ACT, int RES>
__global__ __launch_bounds__(256) void msa_gemm_nt(const float* __restrict__ A, int lda,
                                                   const float* __restrict__ W, int ldw,
                                                   const float* __restrict__ bias,
                                                   const float* __restrict__ resid,
                                                   float* __restrict__ C, int ldc,
                                                   int Kdim) {
  __shared__ float As[8][132];
  __shared__ float Bs[8][132];
  const int tid = threadIdx.x;
  const int m0 = blockIdx.x * 128, n0 = blockIdx.y * 128;
  const int lrow = tid >> 1, lk4 = (tid & 1) << 2;
  const int tx = tid & 15, ty = tid >> 4;
  float acc[8][8];
#pragma unroll
  for (int i = 0; i < 8; ++i)
#pragma unroll
    for (int j = 0; j < 8; ++j) acc[i][j] = 0.f;
  const float* Ald = A + (size_t)(m0 + lrow) * lda + lk4;
  const float* Wld = W + (size_t)(n0 + lrow) * ldw + lk4;
  for (int kt = 0; kt < Kdim; kt += 8) {
    float4 a4 = *(const float4*)(Ald + kt);
    float4 b4 = *(const float4*)(Wld + kt);
    __syncthreads();
    As[lk4 + 0][lrow] = a4.x; As[lk4 + 1][lrow] = a4.y;
    As[lk4 + 2][lrow] = a4.z; As[lk4 + 3][lrow] = a4.w;
    Bs[lk4 + 0][lrow] = b4.x; Bs[lk4 + 1][lrow] = b4.y;
    Bs[lk4 + 2][lrow] = b4.z; Bs[lk4 + 3][lrow] = b4.w;
    __syncthreads();
#pragma unroll
    for (int k = 0; k < 8; ++k) {
      float am[8], bn[8];
      *(float4*)&am[0] = *(const float4*)&As[k][ty * 4];
      *(float4*)&am[4] = *(const float4*)&As[k][ty * 4 + 64];
      *(float4*)&bn[0] = *(const float4*)&Bs[k][tx * 4];
      *(float4*)&bn[4] = *(const float4*)&Bs[k][tx * 4 + 64];
#pragma unroll
      for (int i = 0; i < 8; ++i)
#pragma unroll
        for (int j = 0; j < 8; ++j) acc[i][j] += am[i] * bn[j];
    }
  }
#pragma unroll
  for (int i = 0; i < 8; ++i) {
    const int m = m0 + ty * 4 + (i & 3) + ((i >> 2) << 6);
#pragma unroll
    for (int jh = 0; jh < 2; ++jh) {
      const int n = n0 + tx * 4 + (jh << 6);
      float vv[4];
#pragma unroll
      for (int j = 0; j < 4; ++j) {
        float val = acc[i][jh * 4 + j] + bias[n + j];
        if (ACT == 1) val = val / (1.f + __expf(-val));
        if (RES == 1) val += resid[(size_t)m * ldc + n + j];
        vv[j] = val;
      }
      *(float4*)&C[(size_t)m * ldc + n] = make_float4(vv[0], vv[1], vv[2], vv[3]);
    }
  }
}

// ---------------------------------------------------------------------------
// Precompute keep-bits: keep(b,row,col,bin) =
//   (mask!=0) && (row==0 || col==0 || dist[b,row-1,col-1] < dist_bar[b,bin])
// Packed as bits[((b*256+row)*3 + bin)*4 + cc], bit position = col&63, col=64*cc+lane.
__global__ __launch_bounds__(256) void msa_bits(const float* __restrict__ dist,
                                                const float* __restrict__ dist_bar,
                                                const float* __restrict__ maskg,
                                                unsigned long long* __restrict__ bits) {
  const int gw = blockIdx.x * 4 + (threadIdx.x >> 6);   // 16384 waves = (b,row)
  const int lane = threadIdx.x & 63;
  const int b = gw >> 8, row = gw & 255;
  const float cut0 = dist_bar[b * 3 + 0];
  const float cut1 = dist_bar[b * 3 + 1];
  const float cut2 = dist_bar[b * 3 + 2];
  const float* mrow = maskg + (size_t)b * 65536 + (size_t)row * 256;
  const int rj = (row == 0) ? 1 : row;
  const float* drow = dist + (size_t)b * 65025 + (size_t)(rj - 1) * 255;
  unsigned long long* out = bits + (size_t)gw * 12;
#pragma unroll
  for (int cc = 0; cc < 4; ++cc) {
    const int col = cc * 64 + lane;
    const int cj = (col == 0) ? 1 : col;
    float dv = drow[cj - 1];                // always in-bounds; unused when sup
    bool sup = (row == 0) || (col == 0);
    bool mk = (mrow[col] != 0.f);
    if (sup) dv = -1e30f;                   // always below any cut
    unsigned long long b0 = __ballot(mk && (dv < cut0));
    unsigned long long b1 = __ballot(mk && (dv < cut1));
    unsigned long long b2 = __ballot(mk && (dv < cut2));
    if (lane == 0) { out[cc] = b0; out[4 + cc] = b1; out[8 + cc] = b2; }
  }
}

// ---------------------------------------------------------------------------
// Scores + 3-bin masked softmax. Block per (b,h), 512 threads.
// Lane owns cols 4*lane..4*lane+3 -> one dwordx4 store per (row,bin).
__global__ __launch_bounds__(512) void msa_attn(const float* __restrict__ qg,
                                                const float* __restrict__ kg,
                                                const unsigned long long* __restrict__ bits,
                                                float* __restrict__ attn_out) {
  const int bh = blockIdx.x;
  const int b = bh >> 3, h = bh & 7;
  __shared__ float Klds[256 * 64];   // 64 KiB
  __shared__ float qbuf[32 * 64];    // 8 KiB
  const int tid = threadIdx.x;
  const int w = tid >> 6, lane = tid & 63;
#pragma unroll
  for (int i = 0; i < 8; ++i) {
    int s = tid + i * 512;
    int j = s >> 4, d4 = (s & 15) << 2;
    *(float4*)&Klds[j * 64 + d4] =
        *(const float4*)&kg[((size_t)(b * 256 + j)) * 512 + h * 64 + d4];
  }
  const int rot = (lane & 15) << 2;
  for (int rr = 0; rr < 8; ++rr) {
    __syncthreads();   // qbuf readers from previous iter done; also orders K staging
    {
      int wrow = tid >> 4, d4 = (tid & 15) << 2;
      int grow = (wrow >> 2) * 32 + rr * 4 + (wrow & 3);
      *(float4*)&qbuf[wrow * 64 + d4] =
          *(const float4*)&qg[((size_t)(b * 256 + grow)) * 512 + h * 64 + d4];
    }
    __syncthreads();
    float s_[4][4];
#pragma unroll
    for (int r = 0; r < 4; ++r)
#pragma unroll
      for (int c = 0; c < 4; ++c) s_[r][c] = 0.f;
#pragma unroll
    for (int d4i = 0; d4i < 16; ++d4i) {
      const int dd = (d4i * 4 + rot) & 63;
      float4 k4[4];
#pragma unroll
      for (int c = 0; c < 4; ++c)
        k4[c] = *(const float4*)&Klds[(lane * 4 + c) * 64 + dd];
#pragma unroll
      for (int r = 0; r < 4; ++r) {
        float4 q4 = *(const float4*)&qbuf[(w * 4 + r) * 64 + dd];
#pragma unroll
        for (int c = 0; c < 4; ++c)
          s_[r][c] += q4.x * k4[c].x + q4.y * k4[c].y +
                      q4.z * k4[c].z + q4.w * k4[c].w;
      }
    }
    const int row0 = w * 32 + rr * 4;
#pragma unroll
    for (int r = 0; r < 4; ++r) {
      const int row = row0 + r;
      const unsigned long long* brow =
          bits + (size_t)(b * 256 + row) * 12 + (lane >> 4);
      const unsigned long long wd0 = brow[0];
      const unsigned long long wd1 = brow[4];
      const unsigned long long wd2 = brow[8];
      unsigned int nib[3];
      nib[0] = (unsigned int)(wd0 >> rot) & 0xFu;
      nib[1] = (unsigned int)(wd1 >> rot) & 0xFu;
      nib[2] = (unsigned int)(wd2 >> rot) & 0xFu;
      float sc[4];
#pragma unroll
      for (int c = 0; c < 4; ++c) sc[c] = s_[r][c] * 0.125f;
#pragma unroll
      for (int bin = 0; bin < 3; ++bin) {
        float sd[4];
#pragma unroll
        for (int c = 0; c < 4; ++c)
          sd[c] = ((nib[bin] >> c) & 1u) ? sc[c] : NEGV;
        float m = fmaxf(fmaxf(sd[0], sd[1]), fmaxf(sd[2], sd[3]));
#pragma unroll
        for (int off = 32; off > 0; off >>= 1) m = fmaxf(m, __shfl_xor(m, off));
        float p[4], sum = 0.f;
#pragma unroll
        for (int c = 0; c < 4; ++c) { p[c] = __expf(sd[c] - m); sum += p[c]; }
#pragma unroll
        for (int off = 32; off > 0; off >>= 1) sum += __shfl_xor(sum, off);
        const float inv = 1.f / sum;
        float* op = attn_out + ((size_t)((bin * 64 + b) * 8 + h)) * 65536 +
                    (size_t)row * 256 + lane * 4;
        *(float4*)op = make_float4(p[0] * inv, p[1] * inv, p[2] * inv, p[3] * inv);
      }
    }
  }
}

// ---------------------------------------------------------------------------
// PV: per (b,h,bin) GEMM  MO[256,64] = attn[256,256] @ V[256,64]
__global__ __launch_bounds__(256) void msa_pv(const float* __restrict__ attn,
                                              const float* __restrict__ vg,
                                              float* __restrict__ mo) {
  const int bh = blockIdx.x, bin = blockIdx.y;
  const int b = bh >> 3, h = bh & 7;
  __shared__ float As[16][260];
  __shared__ float Bs[16][64];
  const int tid = threadIdx.x;
  const int tx = tid & 15, ty = tid >> 4;
  const float* Ag = attn + ((size_t)((bin * 64 + b) * 8 + h)) * 65536;
  const float* Vg = vg + (size_t)b * 131072 + h * 64;
  float acc[16][4];
#pragma unroll
  for (int i = 0; i < 16; ++i)
#pragma unroll
    for (int j = 0; j < 4; ++j) acc[i][j] = 0.f;
  for (int kt = 0; kt < 256; kt += 16) {
    __syncthreads();
#pragma unroll
    for (int i = 0; i < 4; ++i) {
      int s = tid + i * 256;
      int qr = s >> 2, k4 = (s & 3) << 2;
      float4 a4 = *(const float4*)&Ag[(size_t)qr * 256 + kt + k4];
      As[k4 + 0][qr] = a4.x; As[k4 + 1][qr] = a4.y;
      As[k4 + 2][qr] = a4.z; As[k4 + 3][qr] = a4.w;
    }
    {
      int kk = tid >> 4, d4 = (tid & 15) << 2;
      *(float4*)&Bs[kk][d4] = *(const float4*)&Vg[(size_t)(kt + kk) * 512 + d4];
    }
    __syncthreads();
#pragma unroll
    for (int kk = 0; kk < 16; ++kk) {
      float a[16], bb[4];
      *(float4*)&a[0]  = *(const float4*)&As[kk][ty * 4];
      *(float4*)&a[4]  = *(const float4*)&As[kk][ty * 4 + 64];
      *(float4*)&a[8]  = *(const float4*)&As[kk][ty * 4 + 128];
      *(float4*)&a[12] = *(const float4*)&As[kk][ty * 4 + 192];
      *(float4*)&bb[0] = *(const float4*)&Bs[kk][tx * 4];
#pragma unroll
      for (int i = 0; i < 16; ++i)
#pragma unroll
        for (int j = 0; j < 4; ++j) acc[i][j] += a[i] * bb[j];
    }
  }
#pragma unroll
  for (int i = 0; i < 16; ++i) {
    int q_ = ty * 4 + (i & 3) + ((i >> 2) << 6);
    float* cp = mo + ((size_t)(b * 256 + q_) * 3 + bin) * 512 + h * 64 + tx * 4;
    *(float4*)cp = make_float4(acc[i][0], acc[i][1], acc[i][2], acc[i][3]);
  }
}

// ---------------------------------------------------------------------------
__global__ __launch_bounds__(256) void msa_ln(const float* __restrict__ h2,
                                              const float* __restrict__ gamma,
                                              const float* __restrict__ beta,
                                              float* __restrict__ outp) {
  const int row = blockIdx.x * 4 + (threadIdx.x >> 6);
  const int lane = threadIdx.x & 63;
  const float* hp = h2 + (size_t)row * 512 + lane * 8;
  float4 v0 = *(const float4*)hp;
  float4 v1 = *(const float4*)(hp + 4);
  float s = v0.x + v0.y + v0.z + v0.w + v1.x + v1.y + v1.z + v1.w;
#pragma unroll
  for (int off = 32; off > 0; off >>= 1) s += __shfl_xor(s, off);
  float mu = s * (1.f / 512.f);
  float d[8] = {v0.x - mu, v0.y - mu, v0.z - mu, v0.w - mu,
                v1.x - mu, v1.y - mu, v1.z - mu, v1.w - mu};
  float sq = 0.f;
#pragma unroll
  for (int j = 0; j < 8; ++j) sq += d[j] * d[j];
#pragma unroll
  for (int off = 32; off > 0; off >>= 1) sq += __shfl_xor(sq, off);
  float inv = 1.f / sqrtf(sq * (1.f / 512.f) + 1e-6f);
  const float* gp = gamma + lane * 8;
  const float* bp = beta + lane * 8;
  float* op = outp + (size_t)row * 512 + lane * 8;
#pragma unroll
  for (int j = 0; j < 8; ++j) op[j] = d[j] * inv * gp[j] + bp[j];
}

// ---------------------------------------------------------------------------
extern "C" void kernel_launch(void* const* d_in, const int* in_sizes, int n_in,
                              void* d_out, int out_size, void* d_ws, size_t ws_size,
                              hipStream_t stream) {
  (void)in_sizes; (void)n_in; (void)out_size; (void)ws_size;
  const float* x        = (const float*)d_in[0];
  const float* dist     = (const float*)d_in[1];
  const float* dist_bar = (const float*)d_in[2];
  const float* mask     = (const float*)d_in[3];
  const float* Wq  = (const float*)d_in[4];  const float* bq  = (const float*)d_in[5];
  const float* Wk  = (const float*)d_in[6];  const float* bk  = (const float*)d_in[7];
  const float* Wv  = (const float*)d_in[8];  const float* bv  = (const float*)d_in[9];
  const float* Wa  = (const float*)d_in[10]; const float* ba  = (const float*)d_in[11];
  const float* Ws1 = (const float*)d_in[12]; const float* bs1 = (const float*)d_in[13];
  const float* Ws2 = (const float*)d_in[14]; const float* bs2 = (const float*)d_in[15];
  const float* gamma = (const float*)d_in[16]; const float* beta = (const float*)d_in[17];

  float* ws = (float*)d_ws;
  const size_t SZ = 8388608;          // 16384 * 512
  float* q     = ws;                  // SZ
  float* k     = ws + SZ;             // SZ
  float* v     = ws + 2 * SZ;         // SZ
  float* mo    = ws + 3 * SZ;         // 3*SZ  [B,N,3,512]
  float* Wcat  = ws + 6 * SZ;         // 786432
  float* bcomb = Wcat + 786432;       // 512
  // bits aliases the mo region: consumed by msa_attn BEFORE msa_pv writes mo.
  unsigned long long* bits = (unsigned long long*)(ws + 3 * SZ);  // 1.57 MB
  float* h1 = q;                      // q dead after attention
  float* h2 = k;                      // k dead after attention
  float* outp = (float*)d_out;        // [B,N,H]
  float* attn = outp + SZ;            // [3,B,8,256,256]

  msa_wcat<<<768, 256, 0, stream>>>(Ws1, Wa, Wcat);
  msa_bcomb<<<2, 256, 0, stream>>>(Ws1, ba, bs1, bcomb);
  msa_bits<<<4096, 256, 0, stream>>>(dist, dist_bar, mask, bits);

  dim3 gproj(128, 4);
  msa_gemm_nt<0, 0><<<gproj, 256, 0, stream>>>(x, 512, Wq, 512, bq, nullptr, q, 512, 512);
  msa_gemm_nt<0, 0><<<gproj, 256, 0, stream>>>(x, 512, Wk, 512, bk, nullptr, k, 512, 512);
  msa_gemm_nt<0, 0><<<gproj, 256, 0, stream>>>(x, 512, Wv, 512, bv, nullptr, v, 512, 512);

  msa_attn<<<512, 512, 0, stream>>>(q, k, bits, attn);
  msa_pv<<<dim3(512, 3), 256, 0, stream>>>(attn, v, mo);

  msa_gemm_nt<1, 0><<<gproj, 256, 0, stream>>>(mo, 1536, Wcat, 1536, bcomb, nullptr,
                                               h1, 512, 1536);
  msa_gemm_nt<0, 1><<<gproj, 256, 0, stream>>>(h1, 512, Ws2, 512, bs2, x, h2, 512, 512);

  msa_ln<<<4096, 256, 0, stream>>>(h2, gamma, beta, outp);
}

// Round 3
// 611.986 us; speedup vs baseline: 4.4909x; 2.0291x over previous
//
#include <hip/hip_runtime.h>
#include <cstddef>

#define NEGV (-1e12f)

// Sizes (fixed): B=64, N=256, H=512, HEADS=8, DK=64, NBINS=3

typedef __attribute__((ext_vector_type(4))) float f32x4;
typedef __attribute__((ext_vector_type(8))) __bf16 bf16x8;

__device__ __forceinline__ unsigned short f2bf(float f) {
  union { float f; unsigned u; } v; v.f = f;
  unsigned r = v.u + 0x7FFFu + ((v.u >> 16) & 1u);   // round-nearest-even
  return (unsigned short)(r >> 16);
}

#define GLDS16(gp, lp)                                                      \
  __builtin_amdgcn_global_load_lds(                                         \
      (const __attribute__((address_space(1))) void*)(gp),                  \
      (__attribute__((address_space(3))) void*)(lp), 16, 0, 0)

// ---------------------------------------------------------------------------
// fp32 -> bf16 elementwise (vectorized x4)
__global__ __launch_bounds__(256) void msa_f2b(const float* __restrict__ in,
                                               unsigned short* __restrict__ out,
                                               int n4) {
  int i = blockIdx.x * 256 + threadIdx.x;
  if (i >= n4) return;
  float4 v = ((const float4*)in)[i];
  ushort4 o;
  o.x = f2bf(v.x); o.y = f2bf(v.y); o.z = f2bf(v.z); o.w = f2bf(v.w);
  ((ushort4*)out)[i] = o;
}

// ---------------------------------------------------------------------------
// Wcat[o][i*512+c] = sum_e Ws1[o, i*512+e] * Wa[i, e, c]  -> bf16 output
__global__ __launch_bounds__(256) void msa_wcat(const float* __restrict__ Ws1,
                                                const float* __restrict__ Wa,
                                                unsigned short* __restrict__ Wcatb) {
  int t = blockIdx.x * 256 + threadIdx.x;
  int c = t & 511;
  int og = (t >> 9) & 127;
  int i = t >> 16;
  const float* wap = Wa + ((size_t)i << 18) + c;
  const float* w0 = Ws1 + (size_t)(og * 4 + 0) * 1536 + i * 512;
  const float* w1 = w0 + 1536;
  const float* w2 = w0 + 3072;
  const float* w3 = w0 + 4608;
  float a0 = 0.f, a1 = 0.f, a2 = 0.f, a3 = 0.f;
  for (int e = 0; e < 512; ++e) {
    float wv = wap[(size_t)e << 9];
    a0 += w0[e] * wv; a1 += w1[e] * wv; a2 += w2[e] * wv; a3 += w3[e] * wv;
  }
  size_t base = (size_t)(og * 4) * 1536 + i * 512 + c;
  Wcatb[base] = f2bf(a0); Wcatb[base + 1536] = f2bf(a1);
  Wcatb[base + 3072] = f2bf(a2); Wcatb[base + 4608] = f2bf(a3);
}

__global__ __launch_bounds__(256) void msa_bcomb(const float* __restrict__ Ws1,
                                                 const float* __restrict__ ba,
                                                 const float* __restrict__ bs1,
                                                 float* __restrict__ bcomb) {
  int o = blockIdx.x * 256 + threadIdx.x;
  float acc = bs1[o];
  for (int cidx = 0; cidx < 1536; ++cidx)
    acc += Ws1[(size_t)o * 1536 + cidx] * ba[cidx];
  bcomb[o] = acc;
}

// ---------------------------------------------------------------------------
// bf16 MFMA NT GEMM: C[m,n] = sum_k A[m,k]*W[n,k] (+bias)(+silu)(+fp32 resid)
// 128x128 tile, BK=32, 4 waves, 4x4 16x16x32 fragments/wave, global_load_lds.
template <int ACT, int RES, int OBF>
__global__ __launch_bounds__(256) void msa_gemm_mfma(
    const unsigned short* __restrict__ A, int lda,
    const unsigned short* __restrict__ W, int ldw,
    const float* __restrict__ bias, const float* __restrict__ resid,
    void* __restrict__ Cout, int ldc, int Kdim) {
  __shared__ __align__(16) unsigned short Asm_[4096];   // [128][32] bf16
  __shared__ __align__(16) unsigned short Bsm_[4096];   // [128][32] bf16
  const int tid = threadIdx.x;
  const int lane = tid & 63, wv = tid >> 6;
  const int m0 = blockIdx.x * 128, n0 = blockIdx.y * 128;
  const int wr = wv >> 1, wc = wv & 1;
  const int fr = lane & 15, fq = lane >> 4;
  f32x4 acc[4][4] = {};
  const int srow = tid >> 2, sc8 = (tid & 3) * 8;
  const unsigned short* Ag0 = A + (size_t)(m0 + srow) * lda + sc8;
  const unsigned short* Ag1 = A + (size_t)(m0 + 64 + srow) * lda + sc8;
  const unsigned short* Wg0 = W + (size_t)(n0 + srow) * ldw + sc8;
  const unsigned short* Wg1 = W + (size_t)(n0 + 64 + srow) * ldw + sc8;
  unsigned short* Asp0 = &Asm_[tid * 8];          // lane-linear: base + lane*16B
  unsigned short* Asp1 = &Asm_[2048 + tid * 8];
  unsigned short* Bsp0 = &Bsm_[tid * 8];
  unsigned short* Bsp1 = &Bsm_[2048 + tid * 8];
  for (int kt = 0; kt < Kdim; kt += 32) {
    __syncthreads();                 // previous tile fully consumed
    GLDS16(Ag0 + kt, Asp0);
    GLDS16(Ag1 + kt, Asp1);
    GLDS16(Wg0 + kt, Bsp0);
    GLDS16(Wg1 + kt, Bsp1);
    __syncthreads();                 // vmcnt(0) drain: tile resident
    bf16x8 af[4], bfr[4];
#pragma unroll
    for (int mf = 0; mf < 4; ++mf)
      af[mf] = *(const bf16x8*)&Asm_[(wr * 64 + mf * 16 + fr) * 32 + fq * 8];
#pragma unroll
    for (int nf = 0; nf < 4; ++nf)
      bfr[nf] = *(const bf16x8*)&Bsm_[(wc * 64 + nf * 16 + fr) * 32 + fq * 8];
#pragma unroll
    for (int mf = 0; mf < 4; ++mf)
#pragma unroll
      for (int nf = 0; nf < 4; ++nf)
        acc[mf][nf] = __builtin_amdgcn_mfma_f32_16x16x32_bf16(
            af[mf], bfr[nf], acc[mf][nf], 0, 0, 0);
  }
#pragma unroll
  for (int mf = 0; mf < 4; ++mf) {
#pragma unroll
    for (int nf = 0; nf < 4; ++nf) {
      const int n = n0 + wc * 64 + nf * 16 + fr;
      const float bval = bias[n];
#pragma unroll
      for (int r = 0; r < 4; ++r) {
        const int m = m0 + wr * 64 + mf * 16 + fq * 4 + r;
        float val = acc[mf][nf][r] + bval;
        if (ACT == 1) val = val / (1.f + __expf(-val));   // silu
        if (RES == 1) val += resid[(size_t)m * ldc + n];
        if (OBF == 1)
          ((unsigned short*)Cout)[(size_t)m * ldc + n] = f2bf(val);
        else
          ((float*)Cout)[(size_t)m * ldc + n] = val;
      }
    }
  }
}

// ---------------------------------------------------------------------------
// Precompute keep-bits (unchanged from round 2)
__global__ __launch_bounds__(256) void msa_bits(const float* __restrict__ dist,
                                                const float* __restrict__ dist_bar,
                                                const float* __restrict__ maskg,
                                                unsigned long long* __restrict__ bits) {
  const int gw = blockIdx.x * 4 + (threadIdx.x >> 6);
  const int lane = threadIdx.x & 63;
  const int b = gw >> 8, row = gw & 255;
  const float cut0 = dist_bar[b * 3 + 0];
  const float cut1 = dist_bar[b * 3 + 1];
  const float cut2 = dist_bar[b * 3 + 2];
  const float* mrow = maskg + (size_t)b * 65536 + (size_t)row * 256;
  const int rj = (row == 0) ? 1 : row;
  const float* drow = dist + (size_t)b * 65025 + (size_t)(rj - 1) * 255;
  unsigned long long* out = bits + (size_t)gw * 12;
#pragma unroll
  for (int cc = 0; cc < 4; ++cc) {
    const int col = cc * 64 + lane;
    const int cj = (col == 0) ? 1 : col;
    float dv = drow[cj - 1];
    bool sup = (row == 0) || (col == 0);
    bool mk = (mrow[col] != 0.f);
    if (sup) dv = -1e30f;
    unsigned long long b0 = __ballot(mk && (dv < cut0));
    unsigned long long b1 = __ballot(mk && (dv < cut1));
    unsigned long long b2 = __ballot(mk && (dv < cut2));
    if (lane == 0) { out[cc] = b0; out[4 + cc] = b1; out[8 + cc] = b2; }
  }
}

// ---------------------------------------------------------------------------
// Scores + 3-bin masked softmax (unchanged from round 2; fp32 q,k)
__global__ __launch_bounds__(512) void msa_attn(const float* __restrict__ qg,
                                                const float* __restrict__ kg,
                                                const unsigned long long* __restrict__ bits,
                                                float* __restrict__ attn_out) {
  const int bh = blockIdx.x;
  const int b = bh >> 3, h = bh & 7;
  __shared__ float Klds[256 * 64];
  __shared__ float qbuf[32 * 64];
  const int tid = threadIdx.x;
  const int w = tid >> 6, lane = tid & 63;
#pragma unroll
  for (int i = 0; i < 8; ++i) {
    int s = tid + i * 512;
    int j = s >> 4, d4 = (s & 15) << 2;
    *(float4*)&Klds[j * 64 + d4] =
        *(const float4*)&kg[((size_t)(b * 256 + j)) * 512 + h * 64 + d4];
  }
  const int rot = (lane & 15) << 2;
  for (int rr = 0; rr < 8; ++rr) {
    __syncthreads();
    {
      int wrow = tid >> 4, d4 = (tid & 15) << 2;
      int grow = (wrow >> 2) * 32 + rr * 4 + (wrow & 3);
      *(float4*)&qbuf[wrow * 64 + d4] =
          *(const float4*)&qg[((size_t)(b * 256 + grow)) * 512 + h * 64 + d4];
    }
    __syncthreads();
    float s_[4][4];
#pragma unroll
    for (int r = 0; r < 4; ++r)
#pragma unroll
      for (int c = 0; c < 4; ++c) s_[r][c] = 0.f;
#pragma unroll
    for (int d4i = 0; d4i < 16; ++d4i) {
      const int dd = (d4i * 4 + rot) & 63;
      float4 k4[4];
#pragma unroll
      for (int c = 0; c < 4; ++c)
        k4[c] = *(const float4*)&Klds[(lane * 4 + c) * 64 + dd];
#pragma unroll
      for (int r = 0; r < 4; ++r) {
        float4 q4 = *(const float4*)&qbuf[(w * 4 + r) * 64 + dd];
#pragma unroll
        for (int c = 0; c < 4; ++c)
          s_[r][c] += q4.x * k4[c].x + q4.y * k4[c].y +
                      q4.z * k4[c].z + q4.w * k4[c].w;
      }
    }
    const int row0 = w * 32 + rr * 4;
#pragma unroll
    for (int r = 0; r < 4; ++r) {
      const int row = row0 + r;
      const unsigned long long* brow =
          bits + (size_t)(b * 256 + row) * 12 + (lane >> 4);
      const unsigned long long wd0 = brow[0];
      const unsigned long long wd1 = brow[4];
      const unsigned long long wd2 = brow[8];
      unsigned int nib[3];
      nib[0] = (unsigned int)(wd0 >> rot) & 0xFu;
      nib[1] = (unsigned int)(wd1 >> rot) & 0xFu;
      nib[2] = (unsigned int)(wd2 >> rot) & 0xFu;
      float sc[4];
#pragma unroll
      for (int c = 0; c < 4; ++c) sc[c] = s_[r][c] * 0.125f;
#pragma unroll
      for (int bin = 0; bin < 3; ++bin) {
        float sd[4];
#pragma unroll
        for (int c = 0; c < 4; ++c)
          sd[c] = ((nib[bin] >> c) & 1u) ? sc[c] : NEGV;
        float m = fmaxf(fmaxf(sd[0], sd[1]), fmaxf(sd[2], sd[3]));
#pragma unroll
        for (int off = 32; off > 0; off >>= 1) m = fmaxf(m, __shfl_xor(m, off));
        float p[4], sum = 0.f;
#pragma unroll
        for (int c = 0; c < 4; ++c) { p[c] = __expf(sd[c] - m); sum += p[c]; }
#pragma unroll
        for (int off = 32; off > 0; off >>= 1) sum += __shfl_xor(sum, off);
        const float inv = 1.f / sum;
        float* op = attn_out + ((size_t)((bin * 64 + b) * 8 + h)) * 65536 +
                    (size_t)row * 256 + lane * 4;
        *(float4*)op = make_float4(p[0] * inv, p[1] * inv, p[2] * inv, p[3] * inv);
      }
    }
  }
}

// ---------------------------------------------------------------------------
// PV: per (b,h,bin) GEMM  MO[256,64] = attn[256,256] @ V[256,64]; bf16 output
__global__ __launch_bounds__(256) void msa_pv(const float* __restrict__ attn,
                                              const float* __restrict__ vg,
                                              unsigned short* __restrict__ mob) {
  const int bh = blockIdx.x, bin = blockIdx.y;
  const int b = bh >> 3, h = bh & 7;
  __shared__ float As[16][260];
  __shared__ float Bs[16][64];
  const int tid = threadIdx.x;
  const int tx = tid & 15, ty = tid >> 4;
  const float* Ag = attn + ((size_t)((bin * 64 + b) * 8 + h)) * 65536;
  const float* Vg = vg + (size_t)b * 131072 + h * 64;
  float acc[16][4];
#pragma unroll
  for (int i = 0; i < 16; ++i)
#pragma unroll
    for (int j = 0; j < 4; ++j) acc[i][j] = 0.f;
  for (int kt = 0; kt < 256; kt += 16) {
    __syncthreads();
#pragma unroll
    for (int i = 0; i < 4; ++i) {
      int s = tid + i * 256;
      int qr = s >> 2, k4 = (s & 3) << 2;
      float4 a4 = *(const float4*)&Ag[(size_t)qr * 256 + kt + k4];
      As[k4 + 0][qr] = a4.x; As[k4 + 1][qr] = a4.y;
      As[k4 + 2][qr] = a4.z; As[k4 + 3][qr] = a4.w;
    }
    {
      int kk = tid >> 4, d4 = (tid & 15) << 2;
      *(float4*)&Bs[kk][d4] = *(const float4*)&Vg[(size_t)(kt + kk) * 512 + d4];
    }
    __syncthreads();
#pragma unroll
    for (int kk = 0; kk < 16; ++kk) {
      float a[16], bb[4];
      *(float4*)&a[0]  = *(const float4*)&As[kk][ty * 4];
      *(float4*)&a[4]  = *(const float4*)&As[kk][ty * 4 + 64];
      *(float4*)&a[8]  = *(const float4*)&As[kk][ty * 4 + 128];
      *(float4*)&a[12] = *(const float4*)&As[kk][ty * 4 + 192];
      *(float4*)&bb[0] = *(const float4*)&Bs[kk][tx * 4];
#pragma unroll
      for (int i = 0; i < 16; ++i)
#pragma unroll
        for (int j = 0; j < 4; ++j) acc[i][j] += a[i] * bb[j];
    }
  }
#pragma unroll
  for (int i = 0; i < 16; ++i) {
    int q_ = ty * 4 + (i & 3) + ((i >> 2) << 6);
    unsigned short* cp = mob + ((size_t)(b * 256 + q_) * 3 + bin) * 512 + h * 64 + tx * 4;
    ushort4 st;
    st.x = f2bf(acc[i][0]); st.y = f2bf(acc[i][1]);
    st.z = f2bf(acc[i][2]); st.w = f2bf(acc[i][3]);
    *(ushort4*)cp = st;
  }
}

// ---------------------------------------------------------------------------
__global__ __launch_bounds__(256) void msa_ln(const float* __restrict__ h2,
                                              const float* __restrict__ gamma,
                                              const float* __restrict__ beta,
                                              float* __restrict__ outp) {
  const int row = blockIdx.x * 4 + (threadIdx.x >> 6);
  const int lane = threadIdx.x & 63;
  const float* hp = h2 + (size_t)row * 512 + lane * 8;
  float4 v0 = *(const float4*)hp;
  float4 v1 = *(const float4*)(hp + 4);
  float s = v0.x + v0.y + v0.z + v0.w + v1.x + v1.y + v1.z + v1.w;
#pragma unroll
  for (int off = 32; off > 0; off >>= 1) s += __shfl_xor(s, off);
  float mu = s * (1.f / 512.f);
  float d[8] = {v0.x - mu, v0.y - mu, v0.z - mu, v0.w - mu,
                v1.x - mu, v1.y - mu, v1.z - mu, v1.w - mu};
  float sq = 0.f;
#pragma unroll
  for (int j = 0; j < 8; ++j) sq += d[j] * d[j];
#pragma unroll
  for (int off = 32; off > 0; off >>= 1) sq += __shfl_xor(sq, off);
  float inv = 1.f / sqrtf(sq * (1.f / 512.f) + 1e-6f);
  const float* gp = gamma + lane * 8;
  const float* bp = beta + lane * 8;
  float* op = outp + (size_t)row * 512 + lane * 8;
#pragma unroll
  for (int j = 0; j < 8; ++j) op[j] = d[j] * inv * gp[j] + bp[j];
}

// ---------------------------------------------------------------------------
extern "C" void kernel_launch(void* const* d_in, const int* in_sizes, int n_in,
                              void* d_out, int out_size, void* d_ws, size_t ws_size,
                              hipStream_t stream) {
  (void)in_sizes; (void)n_in; (void)out_size; (void)ws_size;
  const float* x        = (const float*)d_in[0];
  const float* dist     = (const float*)d_in[1];
  const float* dist_bar = (const float*)d_in[2];
  const float* mask     = (const float*)d_in[3];
  const float* Wq  = (const float*)d_in[4];  const float* bq  = (const float*)d_in[5];
  const float* Wk  = (const float*)d_in[6];  const float* bk  = (const float*)d_in[7];
  const float* Wv  = (const float*)d_in[8];  const float* bv  = (const float*)d_in[9];
  const float* Wa  = (const float*)d_in[10]; const float* ba  = (const float*)d_in[11];
  const float* Ws1 = (const float*)d_in[12]; const float* bs1 = (const float*)d_in[13];
  const float* Ws2 = (const float*)d_in[14]; const float* bs2 = (const float*)d_in[15];
  const float* gamma = (const float*)d_in[16]; const float* beta = (const float*)d_in[17];

  char* w8 = (char*)d_ws;
  const size_t SZ = 8388608;                     // 16384*512 elements
  float* q   = (float*)(w8 + 0);                 //  33.6 MB fp32
  float* k   = (float*)(w8 + 33554432);          //  33.6 MB fp32
  float* v   = (float*)(w8 + 67108864);          //  33.6 MB fp32
  unsigned short* mob = (unsigned short*)(w8 + 100663296);   // 50.3 MB bf16 [16384,1536]
  unsigned long long* bits = (unsigned long long*)(w8 + 100663296); // alias (pre-pv)
  unsigned short* xb   = (unsigned short*)(w8 + 150994944);  // 16.8 MB
  unsigned short* Wqb  = (unsigned short*)(w8 + 167772160);
  unsigned short* Wkb  = (unsigned short*)(w8 + 168296448);
  unsigned short* Wvb  = (unsigned short*)(w8 + 168820736);
  unsigned short* Ws2b = (unsigned short*)(w8 + 169345024);
  unsigned short* Wcatb= (unsigned short*)(w8 + 169869312);  // 1.6 MB
  float* bcomb = (float*)(w8 + 171442176);
  unsigned short* h1b = (unsigned short*)q;      // q dead after attn
  float* h2 = k;                                 // k dead after attn
  float* outp = (float*)d_out;
  float* attn = outp + SZ;                       // [3,B,8,256,256] fp32

  msa_f2b<<<8192, 256, 0, stream>>>(x, xb, 2097152);
  msa_f2b<<<256, 256, 0, stream>>>(Wq, Wqb, 65536);
  msa_f2b<<<256, 256, 0, stream>>>(Wk, Wkb, 65536);
  msa_f2b<<<256, 256, 0, stream>>>(Wv, Wvb, 65536);
  msa_f2b<<<256, 256, 0, stream>>>(Ws2, Ws2b, 65536);
  msa_wcat<<<768, 256, 0, stream>>>(Ws1, Wa, Wcatb);
  msa_bcomb<<<2, 256, 0, stream>>>(Ws1, ba, bs1, bcomb);
  msa_bits<<<4096, 256, 0, stream>>>(dist, dist_bar, mask, bits);

  dim3 gproj(128, 4);
  msa_gemm_mfma<0, 0, 0><<<gproj, 256, 0, stream>>>(xb, 512, Wqb, 512, bq, nullptr, q, 512, 512);
  msa_gemm_mfma<0, 0, 0><<<gproj, 256, 0, stream>>>(xb, 512, Wkb, 512, bk, nullptr, k, 512, 512);
  msa_gemm_mfma<0, 0, 0><<<gproj, 256, 0, stream>>>(xb, 512, Wvb, 512, bv, nullptr, v, 512, 512);

  msa_attn<<<512, 512, 0, stream>>>(q, k, bits, attn);
  msa_pv<<<dim3(512, 3), 256, 0, stream>>>(attn, v, mob);

  // h1b = silu(mob @ Wcatb^T + bcomb)   [bf16 out]
  msa_gemm_mfma<1, 0, 1><<<gproj, 256, 0, stream>>>(mob, 1536, Wcatb, 1536, bcomb, nullptr,
                                                    h1b, 512, 1536);
  // h2 = h1b @ Ws2b^T + bs2 + x          [fp32 out]
  msa_gemm_mfma<0, 1, 0><<<gproj, 256, 0, stream>>>(h1b, 512, Ws2b, 512, bs2, x, h2, 512, 512);

  msa_ln<<<4096, 256, 0, stream>>>(h2, gamma, beta, outp);
}

// Round 4
// 547.291 us; speedup vs baseline: 5.0218x; 1.1182x over previous
//
#include <hip/hip_runtime.h>
#include <cstddef>

#define NEGV (-1e12f)

// Sizes (fixed): B=64, N=256, H=512, HEADS=8, DK=64, NBINS=3

typedef __attribute__((ext_vector_type(4))) float f32x4;
typedef __attribute__((ext_vector_type(8))) __bf16 bf16x8;

__device__ __forceinline__ unsigned short f2bf(float f) {
  union { float f; unsigned u; } v; v.f = f;
  unsigned r = v.u + 0x7FFFu + ((v.u >> 16) & 1u);   // round-nearest-even
  return (unsigned short)(r >> 16);
}

#define GLDS16(gp, lp)                                                      \
  __builtin_amdgcn_global_load_lds(                                         \
      (const __attribute__((address_space(1))) void*)(gp),                  \
      (__attribute__((address_space(3))) void*)(lp), 16, 0, 0)

// ---------------------------------------------------------------------------
// fp32 -> bf16 elementwise (vectorized x4)
__global__ __launch_bounds__(256) void msa_f2b(const float* __restrict__ in,
                                               unsigned short* __restrict__ out,
                                               int n4) {
  int i = blockIdx.x * 256 + threadIdx.x;
  if (i >= n4) return;
  float4 v = ((const float4*)in)[i];
  ushort4 o;
  o.x = f2bf(v.x); o.y = f2bf(v.y); o.z = f2bf(v.z); o.w = f2bf(v.w);
  ((ushort4*)out)[i] = o;
}

// ---------------------------------------------------------------------------
// Tiled Wcat: per bin i, C_i[o][c] = sum_e Ws1[o, i*512+e] * Wa[i, e, c]
// 64x64 tile, BK=16, 256 threads, bf16 output.
__global__ __launch_bounds__(256) void msa_wcat_t(const float* __restrict__ Ws1,
                                                  const float* __restrict__ Wa,
                                                  unsigned short* __restrict__ Wcatb) {
  __shared__ float As[16][68];   // [e][o]
  __shared__ float Bs[16][68];   // [e][c]
  const int i = blockIdx.z;
  const int ob = blockIdx.x * 64, cb = blockIdx.y * 64;
  const int tid = threadIdx.x;
  const int tx = tid & 15, ty = tid >> 4;
  float acc[4][4] = {};
  for (int kt = 0; kt < 512; kt += 16) {
    __syncthreads();
    {
      int o = tid & 63, e4 = (tid >> 6) * 4;
      float4 a4 = *(const float4*)&Ws1[(size_t)(ob + o) * 1536 + i * 512 + kt + e4];
      As[e4 + 0][o] = a4.x; As[e4 + 1][o] = a4.y;
      As[e4 + 2][o] = a4.z; As[e4 + 3][o] = a4.w;
    }
    {
      int e = tid & 15, c4 = (tid >> 4) * 4;
      float4 b4 = *(const float4*)&Wa[((size_t)i << 18) + (size_t)(kt + e) * 512 + cb + c4];
      *(float4*)&Bs[e][c4] = b4;
    }
    __syncthreads();
#pragma unroll
    for (int k = 0; k < 16; ++k) {
      float a[4], bb[4];
      *(float4*)a = *(const float4*)&As[k][ty * 4];
      *(float4*)bb = *(const float4*)&Bs[k][tx * 4];
#pragma unroll
      for (int r = 0; r < 4; ++r)
#pragma unroll
        for (int c = 0; c < 4; ++c) acc[r][c] += a[r] * bb[c];
    }
  }
#pragma unroll
  for (int r = 0; r < 4; ++r)
#pragma unroll
    for (int c = 0; c < 4; ++c)
      Wcatb[(size_t)(ob + ty * 4 + r) * 1536 + i * 512 + cb + tx * 4 + c] =
          f2bf(acc[r][c]);
}

__global__ __launch_bounds__(256) void msa_bcomb(const float* __restrict__ Ws1,
                                                 const float* __restrict__ ba,
                                                 const float* __restrict__ bs1,
                                                 float* __restrict__ bcomb) {
  int o = blockIdx.x * 256 + threadIdx.x;
  float acc = bs1[o];
  for (int cidx = 0; cidx < 1536; ++cidx)
    acc += Ws1[(size_t)o * 1536 + cidx] * ba[cidx];
  bcomb[o] = acc;
}

// ---------------------------------------------------------------------------
// bf16 MFMA NT GEMM (unchanged from round 3)
template <int ACT, int RES, int OBF>
__global__ __launch_bounds__(256) void msa_gemm_mfma(
    const unsigned short* __restrict__ A, int lda,
    const unsigned short* __restrict__ W, int ldw,
    const float* __restrict__ bias, const float* __restrict__ resid,
    void* __restrict__ Cout, int ldc, int Kdim) {
  __shared__ __align__(16) unsigned short Asm_[4096];
  __shared__ __align__(16) unsigned short Bsm_[4096];
  const int tid = threadIdx.x;
  const int lane = tid & 63, wv = tid >> 6;
  const int m0 = blockIdx.x * 128, n0 = blockIdx.y * 128;
  const int wr = wv >> 1, wc = wv & 1;
  const int fr = lane & 15, fq = lane >> 4;
  f32x4 acc[4][4] = {};
  const int srow = tid >> 2, sc8 = (tid & 3) * 8;
  const unsigned short* Ag0 = A + (size_t)(m0 + srow) * lda + sc8;
  const unsigned short* Ag1 = A + (size_t)(m0 + 64 + srow) * lda + sc8;
  const unsigned short* Wg0 = W + (size_t)(n0 + srow) * ldw + sc8;
  const unsigned short* Wg1 = W + (size_t)(n0 + 64 + srow) * ldw + sc8;
  unsigned short* Asp0 = &Asm_[tid * 8];
  unsigned short* Asp1 = &Asm_[2048 + tid * 8];
  unsigned short* Bsp0 = &Bsm_[tid * 8];
  unsigned short* Bsp1 = &Bsm_[2048 + tid * 8];
  for (int kt = 0; kt < Kdim; kt += 32) {
    __syncthreads();
    GLDS16(Ag0 + kt, Asp0);
    GLDS16(Ag1 + kt, Asp1);
    GLDS16(Wg0 + kt, Bsp0);
    GLDS16(Wg1 + kt, Bsp1);
    __syncthreads();
    bf16x8 af[4], bfr[4];
#pragma unroll
    for (int mf = 0; mf < 4; ++mf)
      af[mf] = *(const bf16x8*)&Asm_[(wr * 64 + mf * 16 + fr) * 32 + fq * 8];
#pragma unroll
    for (int nf = 0; nf < 4; ++nf)
      bfr[nf] = *(const bf16x8*)&Bsm_[(wc * 64 + nf * 16 + fr) * 32 + fq * 8];
#pragma unroll
    for (int mf = 0; mf < 4; ++mf)
#pragma unroll
      for (int nf = 0; nf < 4; ++nf)
        acc[mf][nf] = __builtin_amdgcn_mfma_f32_16x16x32_bf16(
            af[mf], bfr[nf], acc[mf][nf], 0, 0, 0);
  }
#pragma unroll
  for (int mf = 0; mf < 4; ++mf) {
#pragma unroll
    for (int nf = 0; nf < 4; ++nf) {
      const int n = n0 + wc * 64 + nf * 16 + fr;
      const float bval = bias[n];
#pragma unroll
      for (int r = 0; r < 4; ++r) {
        const int m = m0 + wr * 64 + mf * 16 + fq * 4 + r;
        float val = acc[mf][nf][r] + bval;
        if (ACT == 1) val = val / (1.f + __expf(-val));
        if (RES == 1) val += resid[(size_t)m * ldc + n];
        if (OBF == 1)
          ((unsigned short*)Cout)[(size_t)m * ldc + n] = f2bf(val);
        else
          ((float*)Cout)[(size_t)m * ldc + n] = val;
      }
    }
  }
}

// ---------------------------------------------------------------------------
// Precompute keep-bits (unchanged)
__global__ __launch_bounds__(256) void msa_bits(const float* __restrict__ dist,
                                                const float* __restrict__ dist_bar,
                                                const float* __restrict__ maskg,
                                                unsigned long long* __restrict__ bits) {
  const int gw = blockIdx.x * 4 + (threadIdx.x >> 6);
  const int lane = threadIdx.x & 63;
  const int b = gw >> 8, row = gw & 255;
  const float cut0 = dist_bar[b * 3 + 0];
  const float cut1 = dist_bar[b * 3 + 1];
  const float cut2 = dist_bar[b * 3 + 2];
  const float* mrow = maskg + (size_t)b * 65536 + (size_t)row * 256;
  const int rj = (row == 0) ? 1 : row;
  const float* drow = dist + (size_t)b * 65025 + (size_t)(rj - 1) * 255;
  unsigned long long* out = bits + (size_t)gw * 12;
#pragma unroll
  for (int cc = 0; cc < 4; ++cc) {
    const int col = cc * 64 + lane;
    const int cj = (col == 0) ? 1 : col;
    float dv = drow[cj - 1];
    bool sup = (row == 0) || (col == 0);
    bool mk = (mrow[col] != 0.f);
    if (sup) dv = -1e30f;
    unsigned long long b0 = __ballot(mk && (dv < cut0));
    unsigned long long b1 = __ballot(mk && (dv < cut1));
    unsigned long long b2 = __ballot(mk && (dv < cut2));
    if (lane == 0) { out[cc] = b0; out[4 + cc] = b1; out[8 + cc] = b2; }
  }
}

// ---------------------------------------------------------------------------
// Scores + 3-bin masked softmax (unchanged; fp32 q,k)
__global__ __launch_bounds__(512) void msa_attn(const float* __restrict__ qg,
                                                const float* __restrict__ kg,
                                                const unsigned long long* __restrict__ bits,
                                                float* __restrict__ attn_out) {
  const int bh = blockIdx.x;
  const int b = bh >> 3, h = bh & 7;
  __shared__ float Klds[256 * 64];
  __shared__ float qbuf[32 * 64];
  const int tid = threadIdx.x;
  const int w = tid >> 6, lane = tid & 63;
#pragma unroll
  for (int i = 0; i < 8; ++i) {
    int s = tid + i * 512;
    int j = s >> 4, d4 = (s & 15) << 2;
    *(float4*)&Klds[j * 64 + d4] =
        *(const float4*)&kg[((size_t)(b * 256 + j)) * 512 + h * 64 + d4];
  }
  const int rot = (lane & 15) << 2;
  for (int rr = 0; rr < 8; ++rr) {
    __syncthreads();
    {
      int wrow = tid >> 4, d4 = (tid & 15) << 2;
      int grow = (wrow >> 2) * 32 + rr * 4 + (wrow & 3);
      *(float4*)&qbuf[wrow * 64 + d4] =
          *(const float4*)&qg[((size_t)(b * 256 + grow)) * 512 + h * 64 + d4];
    }
    __syncthreads();
    float s_[4][4];
#pragma unroll
    for (int r = 0; r < 4; ++r)
#pragma unroll
      for (int c = 0; c < 4; ++c) s_[r][c] = 0.f;
#pragma unroll
    for (int d4i = 0; d4i < 16; ++d4i) {
      const int dd = (d4i * 4 + rot) & 63;
      float4 k4[4];
#pragma unroll
      for (int c = 0; c < 4; ++c)
        k4[c] = *(const float4*)&Klds[(lane * 4 + c) * 64 + dd];
#pragma unroll
      for (int r = 0; r < 4; ++r) {
        float4 q4 = *(const float4*)&qbuf[(w * 4 + r) * 64 + dd];
#pragma unroll
        for (int c = 0; c < 4; ++c)
          s_[r][c] += q4.x * k4[c].x + q4.y * k4[c].y +
                      q4.z * k4[c].z + q4.w * k4[c].w;
      }
    }
    const int row0 = w * 32 + rr * 4;
#pragma unroll
    for (int r = 0; r < 4; ++r) {
      const int row = row0 + r;
      const unsigned long long* brow =
          bits + (size_t)(b * 256 + row) * 12 + (lane >> 4);
      const unsigned long long wd0 = brow[0];
      const unsigned long long wd1 = brow[4];
      const unsigned long long wd2 = brow[8];
      unsigned int nib[3];
      nib[0] = (unsigned int)(wd0 >> rot) & 0xFu;
      nib[1] = (unsigned int)(wd1 >> rot) & 0xFu;
      nib[2] = (unsigned int)(wd2 >> rot) & 0xFu;
      float sc[4];
#pragma unroll
      for (int c = 0; c < 4; ++c) sc[c] = s_[r][c] * 0.125f;
#pragma unroll
      for (int bin = 0; bin < 3; ++bin) {
        float sd[4];
#pragma unroll
        for (int c = 0; c < 4; ++c)
          sd[c] = ((nib[bin] >> c) & 1u) ? sc[c] : NEGV;
        float m = fmaxf(fmaxf(sd[0], sd[1]), fmaxf(sd[2], sd[3]));
#pragma unroll
        for (int off = 32; off > 0; off >>= 1) m = fmaxf(m, __shfl_xor(m, off));
        float p[4], sum = 0.f;
#pragma unroll
        for (int c = 0; c < 4; ++c) { p[c] = __expf(sd[c] - m); sum += p[c]; }
#pragma unroll
        for (int off = 32; off > 0; off >>= 1) sum += __shfl_xor(sum, off);
        const float inv = 1.f / sum;
        float* op = attn_out + ((size_t)((bin * 64 + b) * 8 + h)) * 65536 +
                    (size_t)row * 256 + lane * 4;
        *(float4*)op = make_float4(p[0] * inv, p[1] * inv, p[2] * inv, p[3] * inv);
      }
    }
  }
}

// ---------------------------------------------------------------------------
// PV via MFMA: block per (b,h); bins looped inside (V staged once).
// MO[256,64] = P[256,256] @ V[256,64].  P read fp32 from attn, cvt to bf16.
// V transposed in LDS as bf16 Vt[d][k] (pad 260) -> NT-style B fragments.
__global__ __launch_bounds__(256) void msa_pv_mfma(const float* __restrict__ attn,
                                                   const float* __restrict__ vg,
                                                   unsigned short* __restrict__ mob) {
  const int bh = blockIdx.x;
  const int b = bh >> 3, h = bh & 7;
  __shared__ unsigned short Vt[64][260];
  const int tid = threadIdx.x;
  const int lane = tid & 63, wv = tid >> 6;
  // stage V transposed: thread t owns k-row t
  {
    const float* Vg = vg + (size_t)b * 131072 + h * 64 + (size_t)tid * 512;
#pragma unroll
    for (int d4 = 0; d4 < 64; d4 += 4) {
      float4 v4 = *(const float4*)(Vg + d4);
      Vt[d4 + 0][tid] = f2bf(v4.x);
      Vt[d4 + 1][tid] = f2bf(v4.y);
      Vt[d4 + 2][tid] = f2bf(v4.z);
      Vt[d4 + 3][tid] = f2bf(v4.w);
    }
  }
  __syncthreads();
  const int fr = lane & 15, fq = lane >> 4;
  const int m0 = wv * 64;
  for (int bin = 0; bin < 3; ++bin) {
    const float* Ag = attn + ((size_t)((bin * 64 + b) * 8 + h)) * 65536;
    f32x4 acc[4][4] = {};
    for (int ks = 0; ks < 8; ++ks) {
      bf16x8 bfrag[4];
#pragma unroll
      for (int nf = 0; nf < 4; ++nf)
        bfrag[nf] = *(const bf16x8*)&Vt[nf * 16 + fr][ks * 32 + 8 * fq];
      bf16x8 afrag[4];
#pragma unroll
      for (int mf = 0; mf < 4; ++mf) {
        const float* ap = Ag + (size_t)(m0 + mf * 16 + fr) * 256 + ks * 32 + 8 * fq;
        float4 a0 = *(const float4*)ap;
        float4 a1 = *(const float4*)(ap + 4);
        union { unsigned short u[8]; bf16x8 v; } au;
        au.u[0] = f2bf(a0.x); au.u[1] = f2bf(a0.y);
        au.u[2] = f2bf(a0.z); au.u[3] = f2bf(a0.w);
        au.u[4] = f2bf(a1.x); au.u[5] = f2bf(a1.y);
        au.u[6] = f2bf(a1.z); au.u[7] = f2bf(a1.w);
        afrag[mf] = au.v;
      }
#pragma unroll
      for (int mf = 0; mf < 4; ++mf)
#pragma unroll
        for (int nf = 0; nf < 4; ++nf)
          acc[mf][nf] = __builtin_amdgcn_mfma_f32_16x16x32_bf16(
              afrag[mf], bfrag[nf], acc[mf][nf], 0, 0, 0);
    }
#pragma unroll
    for (int mf = 0; mf < 4; ++mf)
#pragma unroll
      for (int nf = 0; nf < 4; ++nf)
#pragma unroll
        for (int r = 0; r < 4; ++r) {
          const int m = m0 + mf * 16 + fq * 4 + r;
          const int c = nf * 16 + fr;
          mob[((size_t)(b * 256 + m) * 3 + bin) * 512 + h * 64 + c] =
              f2bf(acc[mf][nf][r]);
        }
  }
}

// ---------------------------------------------------------------------------
__global__ __launch_bounds__(256) void msa_ln(const float* __restrict__ h2,
                                              const float* __restrict__ gamma,
                                              const float* __restrict__ beta,
                                              float* __restrict__ outp) {
  const int row = blockIdx.x * 4 + (threadIdx.x >> 6);
  const int lane = threadIdx.x & 63;
  const float* hp = h2 + (size_t)row * 512 + lane * 8;
  float4 v0 = *(const float4*)hp;
  float4 v1 = *(const float4*)(hp + 4);
  float s = v0.x + v0.y + v0.z + v0.w + v1.x + v1.y + v1.z + v1.w;
#pragma unroll
  for (int off = 32; off > 0; off >>= 1) s += __shfl_xor(s, off);
  float mu = s * (1.f / 512.f);
  float d[8] = {v0.x - mu, v0.y - mu, v0.z - mu, v0.w - mu,
                v1.x - mu, v1.y - mu, v1.z - mu, v1.w - mu};
  float sq = 0.f;
#pragma unroll
  for (int j = 0; j < 8; ++j) sq += d[j] * d[j];
#pragma unroll
  for (int off = 32; off > 0; off >>= 1) sq += __shfl_xor(sq, off);
  float inv = 1.f / sqrtf(sq * (1.f / 512.f) + 1e-6f);
  const float* gp = gamma + lane * 8;
  const float* bp = beta + lane * 8;
  float* op = outp + (size_t)row * 512 + lane * 8;
#pragma unroll
  for (int j = 0; j < 8; ++j) op[j] = d[j] * inv * gp[j] + bp[j];
}

// ---------------------------------------------------------------------------
extern "C" void kernel_launch(void* const* d_in, const int* in_sizes, int n_in,
                              void* d_out, int out_size, void* d_ws, size_t ws_size,
                              hipStream_t stream) {
  (void)in_sizes; (void)n_in; (void)out_size; (void)ws_size;
  const float* x        = (const float*)d_in[0];
  const float* dist     = (const float*)d_in[1];
  const float* dist_bar = (const float*)d_in[2];
  const float* mask     = (const float*)d_in[3];
  const float* Wq  = (const float*)d_in[4];  const float* bq  = (const float*)d_in[5];
  const float* Wk  = (const float*)d_in[6];  const float* bk  = (const float*)d_in[7];
  const float* Wv  = (const float*)d_in[8];  const float* bv  = (const float*)d_in[9];
  const float* Wa  = (const float*)d_in[10]; const float* ba  = (const float*)d_in[11];
  const float* Ws1 = (const float*)d_in[12]; const float* bs1 = (const float*)d_in[13];
  const float* Ws2 = (const float*)d_in[14]; const float* bs2 = (const float*)d_in[15];
  const float* gamma = (const float*)d_in[16]; const float* beta = (const float*)d_in[17];

  char* w8 = (char*)d_ws;
  const size_t SZ = 8388608;                     // 16384*512 elements
  float* q   = (float*)(w8 + 0);                 //  33.6 MB fp32
  float* k   = (float*)(w8 + 33554432);          //  33.6 MB fp32
  float* v   = (float*)(w8 + 67108864);          //  33.6 MB fp32
  unsigned short* mob = (unsigned short*)(w8 + 100663296);   // 50.3 MB bf16 [16384,1536]
  unsigned long long* bits = (unsigned long long*)(w8 + 100663296); // alias (pre-pv)
  unsigned short* xb   = (unsigned short*)(w8 + 150994944);  // 16.8 MB
  unsigned short* Wqb  = (unsigned short*)(w8 + 167772160);
  unsigned short* Wkb  = (unsigned short*)(w8 + 168296448);
  unsigned short* Wvb  = (unsigned short*)(w8 + 168820736);
  unsigned short* Ws2b = (unsigned short*)(w8 + 169345024);
  unsigned short* Wcatb= (unsigned short*)(w8 + 169869312);  // 1.6 MB
  float* bcomb = (float*)(w8 + 171442176);
  unsigned short* h1b = (unsigned short*)q;      // q dead after attn
  float* h2 = k;                                 // k dead after attn
  float* outp = (float*)d_out;
  float* attn = outp + SZ;                       // [3,B,8,256,256] fp32

  msa_f2b<<<8192, 256, 0, stream>>>(x, xb, 2097152);
  msa_f2b<<<256, 256, 0, stream>>>(Wq, Wqb, 65536);
  msa_f2b<<<256, 256, 0, stream>>>(Wk, Wkb, 65536);
  msa_f2b<<<256, 256, 0, stream>>>(Wv, Wvb, 65536);
  msa_f2b<<<256, 256, 0, stream>>>(Ws2, Ws2b, 65536);
  msa_wcat_t<<<dim3(8, 8, 3), 256, 0, stream>>>(Ws1, Wa, Wcatb);
  msa_bcomb<<<2, 256, 0, stream>>>(Ws1, ba, bs1, bcomb);
  msa_bits<<<4096, 256, 0, stream>>>(dist, dist_bar, mask, bits);

  dim3 gproj(128, 4);
  msa_gemm_mfma<0, 0, 0><<<gproj, 256, 0, stream>>>(xb, 512, Wqb, 512, bq, nullptr, q, 512, 512);
  msa_gemm_mfma<0, 0, 0><<<gproj, 256, 0, stream>>>(xb, 512, Wkb, 512, bk, nullptr, k, 512, 512);
  msa_gemm_mfma<0, 0, 0><<<gproj, 256, 0, stream>>>(xb, 512, Wvb, 512, bv, nullptr, v, 512, 512);

  msa_attn<<<512, 512, 0, stream>>>(q, k, bits, attn);
  msa_pv_mfma<<<512, 256, 0, stream>>>(attn, v, mob);

  // h1b = silu(mob @ Wcatb^T + bcomb)   [bf16 out]
  msa_gemm_mfma<1, 0, 1><<<gproj, 256, 0, stream>>>(mob, 1536, Wcatb, 1536, bcomb, nullptr,
                                                    h1b, 512, 1536);
  // h2 = h1b @ Ws2b^T + bs2 + x          [fp32 out]
  msa_gemm_mfma<0, 1, 0><<<gproj, 256, 0, stream>>>(h1b, 512, Ws2b, 512, bs2, x, h2, 512, 512);

  msa_ln<<<4096, 256, 0, stream>>>(h2, gamma, beta, outp);
}

// Round 5
// 387.083 us; speedup vs baseline: 7.1003x; 1.4139x over previous
//
#include <hip/hip_runtime.h>
#include <cstddef>

#define NEGV (-1e12f)

// Sizes (fixed): B=64, N=256, H=512, HEADS=8, DK=64, NBINS=3

typedef __attribute__((ext_vector_type(4))) float f32x4;
typedef __attribute__((ext_vector_type(8))) __bf16 bf16x8;

__device__ __forceinline__ unsigned short f2bf(float f) {
  union { float f; unsigned u; } v; v.f = f;
  unsigned r = v.u + 0x7FFFu + ((v.u >> 16) & 1u);   // round-nearest-even
  return (unsigned short)(r >> 16);
}

#define GLDS16(gp, lp)                                                      \
  __builtin_amdgcn_global_load_lds(                                         \
      (const __attribute__((address_space(1))) void*)(gp),                  \
      (__attribute__((address_space(3))) void*)(lp), 16, 0, 0)

// ---------------------------------------------------------------------------
// fp32 -> bf16 elementwise (vectorized x4)
__global__ __launch_bounds__(256) void msa_f2b(const float* __restrict__ in,
                                               unsigned short* __restrict__ out,
                                               int n4) {
  int i = blockIdx.x * 256 + threadIdx.x;
  if (i >= n4) return;
  float4 v = ((const float4*)in)[i];
  ushort4 o;
  o.x = f2bf(v.x); o.y = f2bf(v.y); o.z = f2bf(v.z); o.w = f2bf(v.w);
  ((ushort4*)out)[i] = o;
}

// ---------------------------------------------------------------------------
// Tiled Wcat: per bin i, C_i[o][c] = sum_e Ws1[o, i*512+e] * Wa[i, e, c]
__global__ __launch_bounds__(256) void msa_wcat_t(const float* __restrict__ Ws1,
                                                  const float* __restrict__ Wa,
                                                  unsigned short* __restrict__ Wcatb) {
  __shared__ float As[16][68];   // [e][o]
  __shared__ float Bs[16][68];   // [e][c]
  const int i = blockIdx.z;
  const int ob = blockIdx.x * 64, cb = blockIdx.y * 64;
  const int tid = threadIdx.x;
  const int tx = tid & 15, ty = tid >> 4;
  float acc[4][4] = {};
  for (int kt = 0; kt < 512; kt += 16) {
    __syncthreads();
    {
      int o = tid & 63, e4 = (tid >> 6) * 4;
      float4 a4 = *(const float4*)&Ws1[(size_t)(ob + o) * 1536 + i * 512 + kt + e4];
      As[e4 + 0][o] = a4.x; As[e4 + 1][o] = a4.y;
      As[e4 + 2][o] = a4.z; As[e4 + 3][o] = a4.w;
    }
    {
      int e = tid & 15, c4 = (tid >> 4) * 4;
      float4 b4 = *(const float4*)&Wa[((size_t)i << 18) + (size_t)(kt + e) * 512 + cb + c4];
      *(float4*)&Bs[e][c4] = b4;
    }
    __syncthreads();
#pragma unroll
    for (int k = 0; k < 16; ++k) {
      float a[4], bb[4];
      *(float4*)a = *(const float4*)&As[k][ty * 4];
      *(float4*)bb = *(const float4*)&Bs[k][tx * 4];
#pragma unroll
      for (int r = 0; r < 4; ++r)
#pragma unroll
        for (int c = 0; c < 4; ++c) acc[r][c] += a[r] * bb[c];
    }
  }
#pragma unroll
  for (int r = 0; r < 4; ++r)
#pragma unroll
    for (int c = 0; c < 4; ++c)
      Wcatb[(size_t)(ob + ty * 4 + r) * 1536 + i * 512 + cb + tx * 4 + c] =
          f2bf(acc[r][c]);
}

__global__ __launch_bounds__(256) void msa_bcomb(const float* __restrict__ Ws1,
                                                 const float* __restrict__ ba,
                                                 const float* __restrict__ bs1,
                                                 float* __restrict__ bcomb) {
  int o = blockIdx.x * 256 + threadIdx.x;
  float acc = bs1[o];
  for (int cidx = 0; cidx < 1536; ++cidx)
    acc += Ws1[(size_t)o * 1536 + cidx] * ba[cidx];
  bcomb[o] = acc;
}

// ---------------------------------------------------------------------------
// bf16 MFMA NT GEMM (unchanged structure)
template <int ACT, int RES, int OBF>
__global__ __launch_bounds__(256) void msa_gemm_mfma(
    const unsigned short* __restrict__ A, int lda,
    const unsigned short* __restrict__ W, int ldw,
    const float* __restrict__ bias, const float* __restrict__ resid,
    void* __restrict__ Cout, int ldc, int Kdim) {
  __shared__ __align__(16) unsigned short Asm_[4096];
  __shared__ __align__(16) unsigned short Bsm_[4096];
  const int tid = threadIdx.x;
  const int lane = tid & 63, wv = tid >> 6;
  const int m0 = blockIdx.x * 128, n0 = blockIdx.y * 128;
  const int wr = wv >> 1, wc = wv & 1;
  const int fr = lane & 15, fq = lane >> 4;
  f32x4 acc[4][4] = {};
  const int srow = tid >> 2, sc8 = (tid & 3) * 8;
  const unsigned short* Ag0 = A + (size_t)(m0 + srow) * lda + sc8;
  const unsigned short* Ag1 = A + (size_t)(m0 + 64 + srow) * lda + sc8;
  const unsigned short* Wg0 = W + (size_t)(n0 + srow) * ldw + sc8;
  const unsigned short* Wg1 = W + (size_t)(n0 + 64 + srow) * ldw + sc8;
  unsigned short* Asp0 = &Asm_[tid * 8];
  unsigned short* Asp1 = &Asm_[2048 + tid * 8];
  unsigned short* Bsp0 = &Bsm_[tid * 8];
  unsigned short* Bsp1 = &Bsm_[2048 + tid * 8];
  for (int kt = 0; kt < Kdim; kt += 32) {
    __syncthreads();
    GLDS16(Ag0 + kt, Asp0);
    GLDS16(Ag1 + kt, Asp1);
    GLDS16(Wg0 + kt, Bsp0);
    GLDS16(Wg1 + kt, Bsp1);
    __syncthreads();
    bf16x8 af[4], bfr[4];
#pragma unroll
    for (int mf = 0; mf < 4; ++mf)
      af[mf] = *(const bf16x8*)&Asm_[(wr * 64 + mf * 16 + fr) * 32 + fq * 8];
#pragma unroll
    for (int nf = 0; nf < 4; ++nf)
      bfr[nf] = *(const bf16x8*)&Bsm_[(wc * 64 + nf * 16 + fr) * 32 + fq * 8];
#pragma unroll
    for (int mf = 0; mf < 4; ++mf)
#pragma unroll
      for (int nf = 0; nf < 4; ++nf)
        acc[mf][nf] = __builtin_amdgcn_mfma_f32_16x16x32_bf16(
            af[mf], bfr[nf], acc[mf][nf], 0, 0, 0);
  }
#pragma unroll
  for (int mf = 0; mf < 4; ++mf) {
#pragma unroll
    for (int nf = 0; nf < 4; ++nf) {
      const int n = n0 + wc * 64 + nf * 16 + fr;
      const float bval = bias[n];
#pragma unroll
      for (int r = 0; r < 4; ++r) {
        const int m = m0 + wr * 64 + mf * 16 + fq * 4 + r;
        float val = acc[mf][nf][r] + bval;
        if (ACT == 1) val = val / (1.f + __expf(-val));
        if (RES == 1) val += resid[(size_t)m * ldc + n];
        if (OBF == 1)
          ((unsigned short*)Cout)[(size_t)m * ldc + n] = f2bf(val);
        else
          ((float*)Cout)[(size_t)m * ldc + n] = val;
      }
    }
  }
}

// ---------------------------------------------------------------------------
// Precompute keep-bits (unchanged)
__global__ __launch_bounds__(256) void msa_bits(const float* __restrict__ dist,
                                                const float* __restrict__ dist_bar,
                                                const float* __restrict__ maskg,
                                                unsigned long long* __restrict__ bits) {
  const int gw = blockIdx.x * 4 + (threadIdx.x >> 6);
  const int lane = threadIdx.x & 63;
  const int b = gw >> 8, row = gw & 255;
  const float cut0 = dist_bar[b * 3 + 0];
  const float cut1 = dist_bar[b * 3 + 1];
  const float cut2 = dist_bar[b * 3 + 2];
  const float* mrow = maskg + (size_t)b * 65536 + (size_t)row * 256;
  const int rj = (row == 0) ? 1 : row;
  const float* drow = dist + (size_t)b * 65025 + (size_t)(rj - 1) * 255;
  unsigned long long* out = bits + (size_t)gw * 12;
#pragma unroll
  for (int cc = 0; cc < 4; ++cc) {
    const int col = cc * 64 + lane;
    const int cj = (col == 0) ? 1 : col;
    float dv = drow[cj - 1];
    bool sup = (row == 0) || (col == 0);
    bool mk = (mrow[col] != 0.f);
    if (sup) dv = -1e30f;
    unsigned long long b0 = __ballot(mk && (dv < cut0));
    unsigned long long b1 = __ballot(mk && (dv < cut1));
    unsigned long long b2 = __ballot(mk && (dv < cut2));
    if (lane == 0) { out[cc] = b0; out[4 + cc] = b1; out[8 + cc] = b2; }
  }
}

// ---------------------------------------------------------------------------
// Fused attention: MFMA QK^T + 3-bin masked softmax + MFMA PV, per (b,h).
// 512 threads = 8 waves; each wave owns 32 q-rows (2 tiles of 16).
// LDS: K [256][72] bf16, V^T [64][264] bf16, per-wave P tile [16][264] bf16.
__global__ __launch_bounds__(512) void msa_fused(
    const unsigned short* __restrict__ qb, const unsigned short* __restrict__ kb,
    const unsigned short* __restrict__ vb,
    const unsigned long long* __restrict__ bits,
    float* __restrict__ attn_out, unsigned short* __restrict__ mob) {
  const int bh = blockIdx.x;
  const int b = bh >> 3, h = bh & 7;
  __shared__ __align__(16) unsigned short Kl[256][72];    // 36864 B
  __shared__ __align__(16) unsigned short Vt[64][264];    // 33792 B
  __shared__ __align__(16) unsigned short Pl[8][16][264]; // 67584 B
  const int tid = threadIdx.x;
  const int wv = tid >> 6, lane = tid & 63;
  const int l15 = lane & 15, fq = lane >> 4;
  // --- stage K (row-major, pad 72) ---
  {
    const unsigned short* kgp = kb + (size_t)(b * 256) * 512 + h * 64;
#pragma unroll
    for (int i = 0; i < 4; ++i) {
      int s = tid + i * 512;
      int row = s >> 3, c8 = (s & 7) << 3;
      *(uint4*)&Kl[row][c8] = *(const uint4*)&kgp[(size_t)row * 512 + c8];
    }
  }
  // --- stage V transposed (Vt[d][k], pad 264) ---
  {
    int rv = tid & 255, half = tid >> 8;
    const unsigned short* vgp = vb + (size_t)(b * 256 + rv) * 512 + h * 64 + half * 32;
#pragma unroll
    for (int j4 = 0; j4 < 4; ++j4) {
      unsigned short tmp[8];
      *(uint4*)tmp = *(const uint4*)&vgp[j4 * 8];
#pragma unroll
      for (int j = 0; j < 8; ++j) Vt[half * 32 + j4 * 8 + j][rv] = tmp[j];
    }
  }
  __syncthreads();
#pragma unroll
  for (int mf = 0; mf < 2; ++mf) {
    const int r0 = wv * 32 + mf * 16;
    // Q fragments straight from global (bf16)
    const unsigned short* qgp =
        qb + (size_t)(b * 256 + r0 + l15) * 512 + h * 64 + fq * 8;
    bf16x8 aq0 = *(const bf16x8*)qgp;
    bf16x8 aq1 = *(const bf16x8*)(qgp + 32);
    // S = Q K^T : lane -> S[row=r0+fq*4+r][col=nt*16+l15]
    f32x4 accs[16];
#pragma unroll
    for (int nt = 0; nt < 16; ++nt) {
      bf16x8 bk0 = *(const bf16x8*)&Kl[nt * 16 + l15][fq * 8];
      bf16x8 bk1 = *(const bf16x8*)&Kl[nt * 16 + l15][32 + fq * 8];
      f32x4 a = {};
      a = __builtin_amdgcn_mfma_f32_16x16x32_bf16(aq0, bk0, a, 0, 0, 0);
      a = __builtin_amdgcn_mfma_f32_16x16x32_bf16(aq1, bk1, a, 0, 0, 0);
      accs[nt] = a;
    }
#pragma unroll
    for (int bin = 0; bin < 3; ++bin) {
      float* pbase = attn_out + ((size_t)((bin * 64 + b) * 8 + h)) * 65536;
#pragma unroll
      for (int r = 0; r < 4; ++r) {
        const int row = r0 + fq * 4 + r;
        const unsigned long long* bw =
            bits + (size_t)(b * 256 + row) * 12 + bin * 4;
        const unsigned long long w0 = bw[0], w1 = bw[1], w2 = bw[2], w3 = bw[3];
        float p[16];
        float m = -3e38f;
#pragma unroll
        for (int nt = 0; nt < 16; ++nt) {
          unsigned long long w = (nt < 4) ? w0 : (nt < 8) ? w1 : (nt < 12) ? w2 : w3;
          unsigned keep = (unsigned)(w >> ((nt & 3) * 16 + l15)) & 1u;
          float sv = accs[nt][r] * 0.125f;
          p[nt] = keep ? sv : NEGV;
          m = fmaxf(m, p[nt]);
        }
        m = fmaxf(m, __shfl_xor(m, 1));
        m = fmaxf(m, __shfl_xor(m, 2));
        m = fmaxf(m, __shfl_xor(m, 4));
        m = fmaxf(m, __shfl_xor(m, 8));
        float sum = 0.f;
#pragma unroll
        for (int nt = 0; nt < 16; ++nt) { p[nt] = __expf(p[nt] - m); sum += p[nt]; }
        sum += __shfl_xor(sum, 1);
        sum += __shfl_xor(sum, 2);
        sum += __shfl_xor(sum, 4);
        sum += __shfl_xor(sum, 8);
        const float inv = 1.f / sum;
        float* prow = pbase + (size_t)row * 256 + l15;
#pragma unroll
        for (int nt = 0; nt < 16; ++nt) {
          float val = p[nt] * inv;
          prow[nt * 16] = val;                       // fp32 attn output
          Pl[wv][fq * 4 + r][nt * 16 + l15] = f2bf(val);
        }
      }
      // make this wave's Pl writes visible to its own cross-lane reads
      asm volatile("s_waitcnt lgkmcnt(0)" ::: "memory");
      // PV: O[q][d] = sum_k P[q,k] Vt[d,k]
      f32x4 acco[4] = {};
#pragma unroll
      for (int c = 0; c < 8; ++c) {
        bf16x8 pa = *(const bf16x8*)&Pl[wv][l15][c * 32 + fq * 8];
#pragma unroll
        for (int nf = 0; nf < 4; ++nf) {
          bf16x8 bv = *(const bf16x8*)&Vt[nf * 16 + l15][c * 32 + fq * 8];
          acco[nf] = __builtin_amdgcn_mfma_f32_16x16x32_bf16(pa, bv, acco[nf], 0, 0, 0);
        }
      }
#pragma unroll
      for (int nf = 0; nf < 4; ++nf)
#pragma unroll
        for (int r = 0; r < 4; ++r)
          mob[((size_t)(b * 256 + r0 + fq * 4 + r) * 3 + bin) * 512 +
              h * 64 + nf * 16 + l15] = f2bf(acco[nf][r]);
    }
  }
}

// ---------------------------------------------------------------------------
__global__ __launch_bounds__(256) void msa_ln(const float* __restrict__ h2,
                                              const float* __restrict__ gamma,
                                              const float* __restrict__ beta,
                                              float* __restrict__ outp) {
  const int row = blockIdx.x * 4 + (threadIdx.x >> 6);
  const int lane = threadIdx.x & 63;
  const float* hp = h2 + (size_t)row * 512 + lane * 8;
  float4 v0 = *(const float4*)hp;
  float4 v1 = *(const float4*)(hp + 4);
  float s = v0.x + v0.y + v0.z + v0.w + v1.x + v1.y + v1.z + v1.w;
#pragma unroll
  for (int off = 32; off > 0; off >>= 1) s += __shfl_xor(s, off);
  float mu = s * (1.f / 512.f);
  float d[8] = {v0.x - mu, v0.y - mu, v0.z - mu, v0.w - mu,
                v1.x - mu, v1.y - mu, v1.z - mu, v1.w - mu};
  float sq = 0.f;
#pragma unroll
  for (int j = 0; j < 8; ++j) sq += d[j] * d[j];
#pragma unroll
  for (int off = 32; off > 0; off >>= 1) sq += __shfl_xor(sq, off);
  float inv = 1.f / sqrtf(sq * (1.f / 512.f) + 1e-6f);
  const float* gp = gamma + lane * 8;
  const float* bp = beta + lane * 8;
  float* op = outp + (size_t)row * 512 + lane * 8;
#pragma unroll
  for (int j = 0; j < 8; ++j) op[j] = d[j] * inv * gp[j] + bp[j];
}

// ---------------------------------------------------------------------------
extern "C" void kernel_launch(void* const* d_in, const int* in_sizes, int n_in,
                              void* d_out, int out_size, void* d_ws, size_t ws_size,
                              hipStream_t stream) {
  (void)in_sizes; (void)n_in; (void)out_size; (void)ws_size;
  const float* x        = (const float*)d_in[0];
  const float* dist     = (const float*)d_in[1];
  const float* dist_bar = (const float*)d_in[2];
  const float* mask     = (const float*)d_in[3];
  const float* Wq  = (const float*)d_in[4];  const float* bq  = (const float*)d_in[5];
  const float* Wk  = (const float*)d_in[6];  const float* bk  = (const float*)d_in[7];
  const float* Wv  = (const float*)d_in[8];  const float* bv  = (const float*)d_in[9];
  const float* Wa  = (const float*)d_in[10]; const float* ba  = (const float*)d_in[11];
  const float* Ws1 = (const float*)d_in[12]; const float* bs1 = (const float*)d_in[13];
  const float* Ws2 = (const float*)d_in[14]; const float* bs2 = (const float*)d_in[15];
  const float* gamma = (const float*)d_in[16]; const float* beta = (const float*)d_in[17];

  char* w8 = (char*)d_ws;
  const size_t SZ = 8388608;                       // 16384*512 elements
  unsigned short* qb   = (unsigned short*)(w8 + 0);          // 16.8 MB (later h1b)
  unsigned short* kb   = (unsigned short*)(w8 + 16777216);   // 16.8 MB \ later h2
  unsigned short* vb   = (unsigned short*)(w8 + 33554432);   // 16.8 MB / (fp32 33.6MB)
  unsigned short* mob  = (unsigned short*)(w8 + 50331648);   // 50.3 MB [16384,1536]
  unsigned short* xb   = (unsigned short*)(w8 + 100663296);  // 16.8 MB
  unsigned short* Wqb  = (unsigned short*)(w8 + 117440512);
  unsigned short* Wkb  = (unsigned short*)(w8 + 117964800);
  unsigned short* Wvb  = (unsigned short*)(w8 + 118489088);
  unsigned short* Ws2b = (unsigned short*)(w8 + 119013376);
  unsigned short* Wcatb= (unsigned short*)(w8 + 119537664);  // 1.6 MB
  float* bcomb = (float*)(w8 + 121110528);
  unsigned long long* bits = (unsigned long long*)(w8 + 121112576);  // 1.6 MB
  unsigned short* h1b = qb;                        // qb dead after msa_fused
  float* h2 = (float*)(w8 + 16777216);             // kb+vb dead after msa_fused
  float* outp = (float*)d_out;
  float* attn = outp + SZ;                         // [3,B,8,256,256] fp32

  msa_f2b<<<8192, 256, 0, stream>>>(x, xb, 2097152);
  msa_f2b<<<256, 256, 0, stream>>>(Wq, Wqb, 65536);
  msa_f2b<<<256, 256, 0, stream>>>(Wk, Wkb, 65536);
  msa_f2b<<<256, 256, 0, stream>>>(Wv, Wvb, 65536);
  msa_f2b<<<256, 256, 0, stream>>>(Ws2, Ws2b, 65536);
  msa_wcat_t<<<dim3(8, 8, 3), 256, 0, stream>>>(Ws1, Wa, Wcatb);
  msa_bcomb<<<2, 256, 0, stream>>>(Ws1, ba, bs1, bcomb);
  msa_bits<<<4096, 256, 0, stream>>>(dist, dist_bar, mask, bits);

  dim3 gproj(128, 4);
  msa_gemm_mfma<0, 0, 1><<<gproj, 256, 0, stream>>>(xb, 512, Wqb, 512, bq, nullptr, qb, 512, 512);
  msa_gemm_mfma<0, 0, 1><<<gproj, 256, 0, stream>>>(xb, 512, Wkb, 512, bk, nullptr, kb, 512, 512);
  msa_gemm_mfma<0, 0, 1><<<gproj, 256, 0, stream>>>(xb, 512, Wvb, 512, bv, nullptr, vb, 512, 512);

  msa_fused<<<512, 512, 0, stream>>>(qb, kb, vb, bits, attn, mob);

  // h1b = silu(mob @ Wcatb^T + bcomb)   [bf16 out]
  msa_gemm_mfma<1, 0, 1><<<gproj, 256, 0, stream>>>(mob, 1536, Wcatb, 1536, bcomb, nullptr,
                                                    h1b, 512, 1536);
  // h2 = h1b @ Ws2b^T + bs2 + x          [fp32 out]
  msa_gemm_mfma<0, 1, 0><<<gproj, 256, 0, stream>>>(h1b, 512, Ws2b, 512, bs2, x, h2, 512, 512);

  msa_ln<<<4096, 256, 0, stream>>>(h2, gamma, beta, outp);
}

// Round 6
// 325.550 us; speedup vs baseline: 8.4423x; 1.1890x over previous
//
#include <hip/hip_runtime.h>
#include <cstddef>

#define NEGV (-1e12f)

// Sizes (fixed): B=64, N=256, H=512, HEADS=8, DK=64, NBINS=3

typedef __attribute__((ext_vector_type(4))) float f32x4;
typedef __attribute__((ext_vector_type(8))) __bf16 bf16x8;

__device__ __forceinline__ unsigned short f2bf(float f) {
  union { float f; unsigned u; } v; v.f = f;
  unsigned r = v.u + 0x7FFFu + ((v.u >> 16) & 1u);   // round-nearest-even
  return (unsigned short)(r >> 16);
}

#define GLDS16(gp, lp)                                                      \
  __builtin_amdgcn_global_load_lds(                                         \
      (const __attribute__((address_space(1))) void*)(gp),                  \
      (__attribute__((address_space(3))) void*)(lp), 16, 0, 0)

// ---------------------------------------------------------------------------
// Mega-prep: all independent preprocessing in ONE launch (block-range ladder).
//  [0,8192)      xb = bf16(x)
//  [8192,8448)   Wqkvb rows 0..511    = bf16(Wq)
//  [8448,8704)   Wqkvb rows 512..1023 = bf16(Wk)
//  [8704,8960)   Wqkvb rows 1024..1535= bf16(Wv)
//  [8960,9216)   Ws2b = bf16(Ws2)
//  [9216,9408)   Wcatb tiles (192 blocks: bin, 8x8 of 64x64)
//  [9408,9410)   bcomb
//  [9410]        bqkv concat
//  [9411,13507)  keep-bits
__global__ __launch_bounds__(256) void msa_prep(
    const float* __restrict__ x, const float* __restrict__ Wq,
    const float* __restrict__ Wk, const float* __restrict__ Wv,
    const float* __restrict__ Ws2, const float* __restrict__ Ws1,
    const float* __restrict__ Wa, const float* __restrict__ bq,
    const float* __restrict__ bk, const float* __restrict__ bv,
    const float* __restrict__ ba, const float* __restrict__ bs1,
    const float* __restrict__ dist, const float* __restrict__ dist_bar,
    const float* __restrict__ maskg,
    unsigned short* __restrict__ xb, unsigned short* __restrict__ Wqkvb,
    unsigned short* __restrict__ Ws2b, unsigned short* __restrict__ Wcatb,
    float* __restrict__ bcomb, float* __restrict__ bqkv,
    unsigned long long* __restrict__ bits) {
  __shared__ float As[16][68];
  __shared__ float Bs[16][68];
  const int blk = blockIdx.x;
  const int tid = threadIdx.x;
  if (blk < 8192) {                                   // xb
    int i = blk * 256 + tid;
    float4 v = ((const float4*)x)[i];
    ushort4 o; o.x = f2bf(v.x); o.y = f2bf(v.y); o.z = f2bf(v.z); o.w = f2bf(v.w);
    ((ushort4*)xb)[i] = o;
    return;
  }
  if (blk < 8960) {                                   // weight f2b
    int sel = (blk - 8192) >> 8;                      // 0..2
    int i = ((blk - 8192) & 255) * 256 + tid;
    const float* src = (sel == 0) ? Wq : (sel == 1) ? Wk : Wv;
    unsigned short* dst = Wqkvb + (size_t)sel * 262144;
    float4 v = ((const float4*)src)[i];
    ushort4 o; o.x = f2bf(v.x); o.y = f2bf(v.y); o.z = f2bf(v.z); o.w = f2bf(v.w);
    ((ushort4*)dst)[i] = o;
    return;
  }
  if (blk < 9216) {                                   // Ws2b
    int i = (blk - 8960) * 256 + tid;
    float4 v = ((const float4*)Ws2)[i];
    ushort4 o; o.x = f2bf(v.x); o.y = f2bf(v.y); o.z = f2bf(v.z); o.w = f2bf(v.w);
    ((ushort4*)Ws2b)[i] = o;
    return;
  }
  if (blk < 9408) {                                   // Wcat tile
    const int t = blk - 9216;
    const int i = t >> 6;
    const int ob = ((t >> 3) & 7) * 64, cb = (t & 7) * 64;
    const int tx = tid & 15, ty = tid >> 4;
    float acc[4][4] = {};
    for (int kt = 0; kt < 512; kt += 16) {
      __syncthreads();
      {
        int o = tid & 63, e4 = (tid >> 6) * 4;
        float4 a4 = *(const float4*)&Ws1[(size_t)(ob + o) * 1536 + i * 512 + kt + e4];
        As[e4 + 0][o] = a4.x; As[e4 + 1][o] = a4.y;
        As[e4 + 2][o] = a4.z; As[e4 + 3][o] = a4.w;
      }
      {
        int e = tid & 15, c4 = (tid >> 4) * 4;
        float4 b4 = *(const float4*)&Wa[((size_t)i << 18) + (size_t)(kt + e) * 512 + cb + c4];
        *(float4*)&Bs[e][c4] = b4;
      }
      __syncthreads();
#pragma unroll
      for (int k = 0; k < 16; ++k) {
        float a[4], bb[4];
        *(float4*)a = *(const float4*)&As[k][ty * 4];
        *(float4*)bb = *(const float4*)&Bs[k][tx * 4];
#pragma unroll
        for (int r = 0; r < 4; ++r)
#pragma unroll
          for (int c = 0; c < 4; ++c) acc[r][c] += a[r] * bb[c];
      }
    }
#pragma unroll
    for (int r = 0; r < 4; ++r)
#pragma unroll
      for (int c = 0; c < 4; ++c)
        Wcatb[(size_t)(ob + ty * 4 + r) * 1536 + i * 512 + cb + tx * 4 + c] =
            f2bf(acc[r][c]);
    return;
  }
  if (blk < 9410) {                                   // bcomb
    int o = (blk - 9408) * 256 + tid;
    float acc = bs1[o];
    for (int cidx = 0; cidx < 1536; ++cidx)
      acc += Ws1[(size_t)o * 1536 + cidx] * ba[cidx];
    bcomb[o] = acc;
    return;
  }
  if (blk < 9411) {                                   // bqkv concat
    for (int i = tid; i < 1536; i += 256)
      bqkv[i] = (i < 512) ? bq[i] : (i < 1024) ? bk[i - 512] : bv[i - 1024];
    return;
  }
  {                                                   // keep-bits
    const int gw = (blk - 9411) * 4 + (tid >> 6);
    const int lane = tid & 63;
    const int b = gw >> 8, row = gw & 255;
    const float cut0 = dist_bar[b * 3 + 0];
    const float cut1 = dist_bar[b * 3 + 1];
    const float cut2 = dist_bar[b * 3 + 2];
    const float* mrow = maskg + (size_t)b * 65536 + (size_t)row * 256;
    const int rj = (row == 0) ? 1 : row;
    const float* drow = dist + (size_t)b * 65025 + (size_t)(rj - 1) * 255;
    unsigned long long* out = bits + (size_t)gw * 12;
#pragma unroll
    for (int cc = 0; cc < 4; ++cc) {
      const int col = cc * 64 + lane;
      const int cj = (col == 0) ? 1 : col;
      float dv = drow[cj - 1];
      bool sup = (row == 0) || (col == 0);
      bool mk = (mrow[col] != 0.f);
      if (sup) dv = -1e30f;
      unsigned long long b0 = __ballot(mk && (dv < cut0));
      unsigned long long b1 = __ballot(mk && (dv < cut1));
      unsigned long long b2 = __ballot(mk && (dv < cut2));
      if (lane == 0) { out[cc] = b0; out[4 + cc] = b1; out[8 + cc] = b2; }
    }
  }
}

// ---------------------------------------------------------------------------
// bf16 MFMA NT GEMM, 2-phase double-buffered (stage t+1 before compute t).
template <int ACT, int RES, int OBF>
__global__ __launch_bounds__(256) void msa_gemm_mfma(
    const unsigned short* __restrict__ A, int lda,
    const unsigned short* __restrict__ W, int ldw,
    const float* __restrict__ bias, const float* __restrict__ resid,
    void* __restrict__ Cout, int ldc, int Kdim) {
  __shared__ __align__(16) unsigned short Asm_[2][4096];   // [buf][128][32]
  __shared__ __align__(16) unsigned short Bsm_[2][4096];
  const int tid = threadIdx.x;
  const int lane = tid & 63, wv = tid >> 6;
  const int m0 = blockIdx.x * 128, n0 = blockIdx.y * 128;
  const int wr = wv >> 1, wc = wv & 1;
  const int fr = lane & 15, fq = lane >> 4;
  f32x4 acc[4][4] = {};
  const int srow = tid >> 2, sc8 = (tid & 3) * 8;
  const unsigned short* Ag0 = A + (size_t)(m0 + srow) * lda + sc8;
  const unsigned short* Ag1 = A + (size_t)(m0 + 64 + srow) * lda + sc8;
  const unsigned short* Wg0 = W + (size_t)(n0 + srow) * ldw + sc8;
  const unsigned short* Wg1 = W + (size_t)(n0 + 64 + srow) * ldw + sc8;
  // prologue: stage buffer 0
  GLDS16(Ag0, &Asm_[0][tid * 8]);
  GLDS16(Ag1, &Asm_[0][2048 + tid * 8]);
  GLDS16(Wg0, &Bsm_[0][tid * 8]);
  GLDS16(Wg1, &Bsm_[0][2048 + tid * 8]);
  __syncthreads();
  int cur = 0;
  for (int kt = 0; kt < Kdim; kt += 32) {
    if (kt + 32 < Kdim) {          // issue next tile's loads (overlap w/ MFMA)
      const int nx = cur ^ 1, k2 = kt + 32;
      GLDS16(Ag0 + k2, &Asm_[nx][tid * 8]);
      GLDS16(Ag1 + k2, &Asm_[nx][2048 + tid * 8]);
      GLDS16(Wg0 + k2, &Bsm_[nx][tid * 8]);
      GLDS16(Wg1 + k2, &Bsm_[nx][2048 + tid * 8]);
    }
    bf16x8 af[4], bfr[4];
#pragma unroll
    for (int mf = 0; mf < 4; ++mf)
      af[mf] = *(const bf16x8*)&Asm_[cur][(wr * 64 + mf * 16 + fr) * 32 + fq * 8];
#pragma unroll
    for (int nf = 0; nf < 4; ++nf)
      bfr[nf] = *(const bf16x8*)&Bsm_[cur][(wc * 64 + nf * 16 + fr) * 32 + fq * 8];
#pragma unroll
    for (int mf = 0; mf < 4; ++mf)
#pragma unroll
      for (int nf = 0; nf < 4; ++nf)
        acc[mf][nf] = __builtin_amdgcn_mfma_f32_16x16x32_bf16(
            af[mf], bfr[nf], acc[mf][nf], 0, 0, 0);
    __syncthreads();               // drains vmcnt: next buffer resident
    cur ^= 1;
  }
#pragma unroll
  for (int mf = 0; mf < 4; ++mf) {
#pragma unroll
    for (int nf = 0; nf < 4; ++nf) {
      const int n = n0 + wc * 64 + nf * 16 + fr;
      const float bval = bias[n];
#pragma unroll
      for (int r = 0; r < 4; ++r) {
        const int m = m0 + wr * 64 + mf * 16 + fq * 4 + r;
        float val = acc[mf][nf][r] + bval;
        if (ACT == 1) val = val / (1.f + __expf(-val));
        if (RES == 1) val += resid[(size_t)m * ldc + n];
        if (OBF == 1)
          ((unsigned short*)Cout)[(size_t)m * ldc + n] = f2bf(val);
        else
          ((float*)Cout)[(size_t)m * ldc + n] = val;
      }
    }
  }
}

// ---------------------------------------------------------------------------
// Fused attention: MFMA QK^T + 3-bin masked softmax + MFMA PV, per (b,h).
// q/k/v are column slices (0/512/1024) of qkvb [16384][1536] bf16.
__global__ __launch_bounds__(512) void msa_fused(
    const unsigned short* __restrict__ qkvb,
    const unsigned long long* __restrict__ bits,
    float* __restrict__ attn_out, unsigned short* __restrict__ mob) {
  const int bh = blockIdx.x;
  const int b = bh >> 3, h = bh & 7;
  __shared__ __align__(16) unsigned short Kl[256][72];
  __shared__ __align__(16) unsigned short Vt[64][264];
  __shared__ __align__(16) unsigned short Pl[8][16][264];
  const int tid = threadIdx.x;
  const int wv = tid >> 6, lane = tid & 63;
  const int l15 = lane & 15, fq = lane >> 4;
  // --- stage K ---
  {
    const unsigned short* kgp = qkvb + (size_t)(b * 256) * 1536 + 512 + h * 64;
#pragma unroll
    for (int i = 0; i < 4; ++i) {
      int s = tid + i * 512;
      int row = s >> 3, c8 = (s & 7) << 3;
      *(uint4*)&Kl[row][c8] = *(const uint4*)&kgp[(size_t)row * 1536 + c8];
    }
  }
  // --- stage V transposed ---
  {
    int rv = tid & 255, half = tid >> 8;
    const unsigned short* vgp =
        qkvb + (size_t)(b * 256 + rv) * 1536 + 1024 + h * 64 + half * 32;
#pragma unroll
    for (int j4 = 0; j4 < 4; ++j4) {
      unsigned short tmp[8];
      *(uint4*)tmp = *(const uint4*)&vgp[j4 * 8];
#pragma unroll
      for (int j = 0; j < 8; ++j) Vt[half * 32 + j4 * 8 + j][rv] = tmp[j];
    }
  }
  __syncthreads();
#pragma unroll
  for (int mf = 0; mf < 2; ++mf) {
    const int r0 = wv * 32 + mf * 16;
    const unsigned short* qgp =
        qkvb + (size_t)(b * 256 + r0 + l15) * 1536 + h * 64 + fq * 8;
    bf16x8 aq0 = *(const bf16x8*)qgp;
    bf16x8 aq1 = *(const bf16x8*)(qgp + 32);
    f32x4 accs[16];
#pragma unroll
    for (int nt = 0; nt < 16; ++nt) {
      bf16x8 bk0 = *(const bf16x8*)&Kl[nt * 16 + l15][fq * 8];
      bf16x8 bk1 = *(const bf16x8*)&Kl[nt * 16 + l15][32 + fq * 8];
      f32x4 a = {};
      a = __builtin_amdgcn_mfma_f32_16x16x32_bf16(aq0, bk0, a, 0, 0, 0);
      a = __builtin_amdgcn_mfma_f32_16x16x32_bf16(aq1, bk1, a, 0, 0, 0);
      accs[nt] = a;
    }
#pragma unroll
    for (int bin = 0; bin < 3; ++bin) {
      float* pbase = attn_out + ((size_t)((bin * 64 + b) * 8 + h)) * 65536;
#pragma unroll
      for (int r = 0; r < 4; ++r) {
        const int row = r0 + fq * 4 + r;
        const unsigned long long* bw =
            bits + (size_t)(b * 256 + row) * 12 + bin * 4;
        const unsigned long long w0 = bw[0], w1 = bw[1], w2 = bw[2], w3 = bw[3];
        float p[16];
        float m = -3e38f;
#pragma unroll
        for (int nt = 0; nt < 16; ++nt) {
          unsigned long long w = (nt < 4) ? w0 : (nt < 8) ? w1 : (nt < 12) ? w2 : w3;
          unsigned keep = (unsigned)(w >> ((nt & 3) * 16 + l15)) & 1u;
          float sv = accs[nt][r] * 0.125f;
          p[nt] = keep ? sv : NEGV;
          m = fmaxf(m, p[nt]);
        }
        m = fmaxf(m, __shfl_xor(m, 1));
        m = fmaxf(m, __shfl_xor(m, 2));
        m = fmaxf(m, __shfl_xor(m, 4));
        m = fmaxf(m, __shfl_xor(m, 8));
        float sum = 0.f;
#pragma unroll
        for (int nt = 0; nt < 16; ++nt) { p[nt] = __expf(p[nt] - m); sum += p[nt]; }
        sum += __shfl_xor(sum, 1);
        sum += __shfl_xor(sum, 2);
        sum += __shfl_xor(sum, 4);
        sum += __shfl_xor(sum, 8);
        const float inv = 1.f / sum;
        float* prow = pbase + (size_t)row * 256 + l15;
#pragma unroll
        for (int nt = 0; nt < 16; ++nt) {
          float val = p[nt] * inv;
          prow[nt * 16] = val;
          Pl[wv][fq * 4 + r][nt * 16 + l15] = f2bf(val);
        }
      }
      asm volatile("s_waitcnt lgkmcnt(0)" ::: "memory");
      f32x4 acco[4] = {};
#pragma unroll
      for (int c = 0; c < 8; ++c) {
        bf16x8 pa = *(const bf16x8*)&Pl[wv][l15][c * 32 + fq * 8];
#pragma unroll
        for (int nf = 0; nf < 4; ++nf) {
          bf16x8 bv = *(const bf16x8*)&Vt[nf * 16 + l15][c * 32 + fq * 8];
          acco[nf] = __builtin_amdgcn_mfma_f32_16x16x32_bf16(pa, bv, acco[nf], 0, 0, 0);
        }
      }
#pragma unroll
      for (int nf = 0; nf < 4; ++nf)
#pragma unroll
        for (int r = 0; r < 4; ++r)
          mob[((size_t)(b * 256 + r0 + fq * 4 + r) * 3 + bin) * 512 +
              h * 64 + nf * 16 + l15] = f2bf(acco[nf][r]);
    }
  }
}

// ---------------------------------------------------------------------------
__global__ __launch_bounds__(256) void msa_ln(const float* __restrict__ h2,
                                              const float* __restrict__ gamma,
                                              const float* __restrict__ beta,
                                              float* __restrict__ outp) {
  const int row = blockIdx.x * 4 + (threadIdx.x >> 6);
  const int lane = threadIdx.x & 63;
  const float* hp = h2 + (size_t)row * 512 + lane * 8;
  float4 v0 = *(const float4*)hp;
  float4 v1 = *(const float4*)(hp + 4);
  float s = v0.x + v0.y + v0.z + v0.w + v1.x + v1.y + v1.z + v1.w;
#pragma unroll
  for (int off = 32; off > 0; off >>= 1) s += __shfl_xor(s, off);
  float mu = s * (1.f / 512.f);
  float d[8] = {v0.x - mu, v0.y - mu, v0.z - mu, v0.w - mu,
                v1.x - mu, v1.y - mu, v1.z - mu, v1.w - mu};
  float sq = 0.f;
#pragma unroll
  for (int j = 0; j < 8; ++j) sq += d[j] * d[j];
#pragma unroll
  for (int off = 32; off > 0; off >>= 1) sq += __shfl_xor(sq, off);
  float inv = 1.f / sqrtf(sq * (1.f / 512.f) + 1e-6f);
  const float* gp = gamma + lane * 8;
  const float* bp = beta + lane * 8;
  float* op = outp + (size_t)row * 512 + lane * 8;
#pragma unroll
  for (int j = 0; j < 8; ++j) op[j] = d[j] * inv * gp[j] + bp[j];
}

// ---------------------------------------------------------------------------
extern "C" void kernel_launch(void* const* d_in, const int* in_sizes, int n_in,
                              void* d_out, int out_size, void* d_ws, size_t ws_size,
                              hipStream_t stream) {
  (void)in_sizes; (void)n_in; (void)out_size; (void)ws_size;
  const float* x        = (const float*)d_in[0];
  const float* dist     = (const float*)d_in[1];
  const float* dist_bar = (const float*)d_in[2];
  const float* mask     = (const float*)d_in[3];
  const float* Wq  = (const float*)d_in[4];  const float* bq  = (const float*)d_in[5];
  const float* Wk  = (const float*)d_in[6];  const float* bk  = (const float*)d_in[7];
  const float* Wv  = (const float*)d_in[8];  const float* bv  = (const float*)d_in[9];
  const float* Wa  = (const float*)d_in[10]; const float* ba  = (const float*)d_in[11];
  const float* Ws1 = (const float*)d_in[12]; const float* bs1 = (const float*)d_in[13];
  const float* Ws2 = (const float*)d_in[14]; const float* bs2 = (const float*)d_in[15];
  const float* gamma = (const float*)d_in[16]; const float* beta = (const float*)d_in[17];

  char* w8 = (char*)d_ws;
  const size_t SZ = 8388608;                         // 16384*512
  unsigned short* qkvb = (unsigned short*)(w8 + 0);            // 50.3 MB [16384][1536]
  unsigned short* mob  = (unsigned short*)(w8 + 50331648);     // 50.3 MB [16384][1536]
  unsigned short* xb   = (unsigned short*)(w8 + 100663296);    // 16.8 MB
  unsigned short* Wqkvb= (unsigned short*)(w8 + 117440512);    // 1.6 MB [1536][512]
  unsigned short* Ws2b = (unsigned short*)(w8 + 119013376);    // 0.5 MB
  unsigned short* Wcatb= (unsigned short*)(w8 + 119537664);    // 1.6 MB [512][1536]
  float* bcomb = (float*)(w8 + 121110528);                     // 2 KB
  float* bqkv  = (float*)(w8 + 121112576);                     // 6 KB
  unsigned long long* bits = (unsigned long long*)(w8 + 121118720);  // 1.6 MB
  unsigned short* h1b = qkvb;                        // qkvb dead after msa_fused
  float* h2 = (float*)(w8 + 16777216);               // fits in qkvb region tail
  float* outp = (float*)d_out;
  float* attn = outp + SZ;                           // [3,B,8,256,256] fp32

  msa_prep<<<13507, 256, 0, stream>>>(x, Wq, Wk, Wv, Ws2, Ws1, Wa, bq, bk, bv,
                                      ba, bs1, dist, dist_bar, mask,
                                      xb, Wqkvb, Ws2b, Wcatb, bcomb, bqkv, bits);

  // qkv = x @ [Wq;Wk;Wv]^T + bqkv   (bf16 out, one GEMM, 1536 blocks)
  msa_gemm_mfma<0, 0, 1><<<dim3(128, 12), 256, 0, stream>>>(
      xb, 512, Wqkvb, 512, bqkv, nullptr, qkvb, 1536, 512);

  msa_fused<<<512, 512, 0, stream>>>(qkvb, bits, attn, mob);

  // h1b = silu(mob @ Wcatb^T + bcomb)   [bf16 out]
  msa_gemm_mfma<1, 0, 1><<<dim3(128, 4), 256, 0, stream>>>(
      mob, 1536, Wcatb, 1536, bcomb, nullptr, h1b, 512, 1536);
  // h2 = h1b @ Ws2b^T + bs2 + x          [fp32 out]
  msa_gemm_mfma<0, 1, 0><<<dim3(128, 4), 256, 0, stream>>>(
      h1b, 512, Ws2b, 512, bs2, x, h2, 512, 512);

  msa_ln<<<4096, 256, 0, stream>>>(h2, gamma, beta, outp);
}

// Round 7
// 325.089 us; speedup vs baseline: 8.4543x; 1.0014x over previous
//
#include <hip/hip_runtime.h>
#include <cstddef>

#define NEGV (-1e12f)

// Sizes (fixed): B=64, N=256, H=512, HEADS=8, DK=64, NBINS=3

typedef __attribute__((ext_vector_type(4))) float f32x4;
typedef __attribute__((ext_vector_type(8))) __bf16 bf16x8;

__device__ __forceinline__ unsigned short f2bf(float f) {
  union { float f; unsigned u; } v; v.f = f;
  unsigned r = v.u + 0x7FFFu + ((v.u >> 16) & 1u);   // round-nearest-even
  return (unsigned short)(r >> 16);
}

#define GLDS16(gp, lp)                                                      \
  __builtin_amdgcn_global_load_lds(                                         \
      (const __attribute__((address_space(1))) void*)(gp),                  \
      (__attribute__((address_space(3))) void*)(lp), 16, 0, 0)

// ---------------------------------------------------------------------------
// Mega-prep (unchanged from round 6)
__global__ __launch_bounds__(256) void msa_prep(
    const float* __restrict__ x, const float* __restrict__ Wq,
    const float* __restrict__ Wk, const float* __restrict__ Wv,
    const float* __restrict__ Ws2, const float* __restrict__ Ws1,
    const float* __restrict__ Wa, const float* __restrict__ bq,
    const float* __restrict__ bk, const float* __restrict__ bv,
    const float* __restrict__ ba, const float* __restrict__ bs1,
    const float* __restrict__ dist, const float* __restrict__ dist_bar,
    const float* __restrict__ maskg,
    unsigned short* __restrict__ xb, unsigned short* __restrict__ Wqkvb,
    unsigned short* __restrict__ Ws2b, unsigned short* __restrict__ Wcatb,
    float* __restrict__ bcomb, float* __restrict__ bqkv,
    unsigned long long* __restrict__ bits) {
  __shared__ float As[16][68];
  __shared__ float Bs[16][68];
  const int blk = blockIdx.x;
  const int tid = threadIdx.x;
  if (blk < 8192) {                                   // xb
    int i = blk * 256 + tid;
    float4 v = ((const float4*)x)[i];
    ushort4 o; o.x = f2bf(v.x); o.y = f2bf(v.y); o.z = f2bf(v.z); o.w = f2bf(v.w);
    ((ushort4*)xb)[i] = o;
    return;
  }
  if (blk < 8960) {                                   // weight f2b
    int sel = (blk - 8192) >> 8;                      // 0..2
    int i = ((blk - 8192) & 255) * 256 + tid;
    const float* src = (sel == 0) ? Wq : (sel == 1) ? Wk : Wv;
    unsigned short* dst = Wqkvb + (size_t)sel * 262144;
    float4 v = ((const float4*)src)[i];
    ushort4 o; o.x = f2bf(v.x); o.y = f2bf(v.y); o.z = f2bf(v.z); o.w = f2bf(v.w);
    ((ushort4*)dst)[i] = o;
    return;
  }
  if (blk < 9216) {                                   // Ws2b
    int i = (blk - 8960) * 256 + tid;
    float4 v = ((const float4*)Ws2)[i];
    ushort4 o; o.x = f2bf(v.x); o.y = f2bf(v.y); o.z = f2bf(v.z); o.w = f2bf(v.w);
    ((ushort4*)Ws2b)[i] = o;
    return;
  }
  if (blk < 9408) {                                   // Wcat tile
    const int t = blk - 9216;
    const int i = t >> 6;
    const int ob = ((t >> 3) & 7) * 64, cb = (t & 7) * 64;
    const int tx = tid & 15, ty = tid >> 4;
    float acc[4][4] = {};
    for (int kt = 0; kt < 512; kt += 16) {
      __syncthreads();
      {
        int o = tid & 63, e4 = (tid >> 6) * 4;
        float4 a4 = *(const float4*)&Ws1[(size_t)(ob + o) * 1536 + i * 512 + kt + e4];
        As[e4 + 0][o] = a4.x; As[e4 + 1][o] = a4.y;
        As[e4 + 2][o] = a4.z; As[e4 + 3][o] = a4.w;
      }
      {
        int e = tid & 15, c4 = (tid >> 4) * 4;
        float4 b4 = *(const float4*)&Wa[((size_t)i << 18) + (size_t)(kt + e) * 512 + cb + c4];
        *(float4*)&Bs[e][c4] = b4;
      }
      __syncthreads();
#pragma unroll
      for (int k = 0; k < 16; ++k) {
        float a[4], bb[4];
        *(float4*)a = *(const float4*)&As[k][ty * 4];
        *(float4*)bb = *(const float4*)&Bs[k][tx * 4];
#pragma unroll
        for (int r = 0; r < 4; ++r)
#pragma unroll
          for (int c = 0; c < 4; ++c) acc[r][c] += a[r] * bb[c];
      }
    }
#pragma unroll
    for (int r = 0; r < 4; ++r)
#pragma unroll
      for (int c = 0; c < 4; ++c)
        Wcatb[(size_t)(ob + ty * 4 + r) * 1536 + i * 512 + cb + tx * 4 + c] =
            f2bf(acc[r][c]);
    return;
  }
  if (blk < 9410) {                                   // bcomb
    int o = (blk - 9408) * 256 + tid;
    float acc = bs1[o];
    for (int cidx = 0; cidx < 1536; ++cidx)
      acc += Ws1[(size_t)o * 1536 + cidx] * ba[cidx];
    bcomb[o] = acc;
    return;
  }
  if (blk < 9411) {                                   // bqkv concat
    for (int i = tid; i < 1536; i += 256)
      bqkv[i] = (i < 512) ? bq[i] : (i < 1024) ? bk[i - 512] : bv[i - 1024];
    return;
  }
  {                                                   // keep-bits
    const int gw = (blk - 9411) * 4 + (tid >> 6);
    const int lane = tid & 63;
    const int b = gw >> 8, row = gw & 255;
    const float cut0 = dist_bar[b * 3 + 0];
    const float cut1 = dist_bar[b * 3 + 1];
    const float cut2 = dist_bar[b * 3 + 2];
    const float* mrow = maskg + (size_t)b * 65536 + (size_t)row * 256;
    const int rj = (row == 0) ? 1 : row;
    const float* drow = dist + (size_t)b * 65025 + (size_t)(rj - 1) * 255;
    unsigned long long* out = bits + (size_t)gw * 12;
#pragma unroll
    for (int cc = 0; cc < 4; ++cc) {
      const int col = cc * 64 + lane;
      const int cj = (col == 0) ? 1 : col;
      float dv = drow[cj - 1];
      bool sup = (row == 0) || (col == 0);
      bool mk = (mrow[col] != 0.f);
      if (sup) dv = -1e30f;
      unsigned long long b0 = __ballot(mk && (dv < cut0));
      unsigned long long b1 = __ballot(mk && (dv < cut1));
      unsigned long long b2 = __ballot(mk && (dv < cut2));
      if (lane == 0) { out[cc] = b0; out[4 + cc] = b1; out[8 + cc] = b2; }
    }
  }
}

// ---------------------------------------------------------------------------
// bf16 MFMA NT GEMM, 2-phase double-buffered, parameterized K-step BK (32/64).
// BK=64: 2x MFMA per barrier drain (for grid-limited 2-block/CU shapes).
template <int ACT, int RES, int OBF, int BK>
__global__ __launch_bounds__(256) void msa_gemm_mfma(
    const unsigned short* __restrict__ A, int lda,
    const unsigned short* __restrict__ W, int ldw,
    const float* __restrict__ bias, const float* __restrict__ resid,
    void* __restrict__ Cout, int ldc, int Kdim) {
  constexpr int KSUB = BK / 32;            // k-subtiles per step
  constexpr int RPC = BK / 8;              // 16B chunks per row
  constexpr int CPT = (128 * RPC) / 256;   // chunks per thread
  __shared__ __align__(16) unsigned short Asm_[2][128 * BK];
  __shared__ __align__(16) unsigned short Bsm_[2][128 * BK];
  const int tid = threadIdx.x;
  const int lane = tid & 63, wv = tid >> 6;
  const int m0 = blockIdx.x * 128, n0 = blockIdx.y * 128;
  const int wr = wv >> 1, wc = wv & 1;
  const int fr = lane & 15, fq = lane >> 4;
  f32x4 acc[4][4] = {};
  const unsigned short* Ag[CPT];
  const unsigned short* Wg[CPT];
#pragma unroll
  for (int i = 0; i < CPT; ++i) {
    int c = tid + i * 256;
    int row = c / RPC, j = c % RPC;
    Ag[i] = A + (size_t)(m0 + row) * lda + j * 8;
    Wg[i] = W + (size_t)(n0 + row) * ldw + j * 8;
  }
  // prologue: stage buffer 0
#pragma unroll
  for (int i = 0; i < CPT; ++i) {
    GLDS16(Ag[i], &Asm_[0][(tid + i * 256) * 8]);
    GLDS16(Wg[i], &Bsm_[0][(tid + i * 256) * 8]);
  }
  __syncthreads();
  int cur = 0;
  for (int kt = 0; kt < Kdim; kt += BK) {
    if (kt + BK < Kdim) {          // issue next tile's loads (overlap w/ MFMA)
      const int nx = cur ^ 1, k2 = kt + BK;
#pragma unroll
      for (int i = 0; i < CPT; ++i) {
        GLDS16(Ag[i] + k2, &Asm_[nx][(tid + i * 256) * 8]);
        GLDS16(Wg[i] + k2, &Bsm_[nx][(tid + i * 256) * 8]);
      }
    }
#pragma unroll
    for (int ks = 0; ks < KSUB; ++ks) {
      bf16x8 af[4], bfr[4];
#pragma unroll
      for (int mf = 0; mf < 4; ++mf)
        af[mf] = *(const bf16x8*)&Asm_[cur][(wr * 64 + mf * 16 + fr) * BK + ks * 32 + fq * 8];
#pragma unroll
      for (int nf = 0; nf < 4; ++nf)
        bfr[nf] = *(const bf16x8*)&Bsm_[cur][(wc * 64 + nf * 16 + fr) * BK + ks * 32 + fq * 8];
#pragma unroll
      for (int mf = 0; mf < 4; ++mf)
#pragma unroll
        for (int nf = 0; nf < 4; ++nf)
          acc[mf][nf] = __builtin_amdgcn_mfma_f32_16x16x32_bf16(
              af[mf], bfr[nf], acc[mf][nf], 0, 0, 0);
    }
    __syncthreads();               // drains vmcnt: next buffer resident
    cur ^= 1;
  }
#pragma unroll
  for (int mf = 0; mf < 4; ++mf) {
#pragma unroll
    for (int nf = 0; nf < 4; ++nf) {
      const int n = n0 + wc * 64 + nf * 16 + fr;
      const float bval = bias[n];
#pragma unroll
      for (int r = 0; r < 4; ++r) {
        const int m = m0 + wr * 64 + mf * 16 + fq * 4 + r;
        float val = acc[mf][nf][r] + bval;
        if (ACT == 1) val = val / (1.f + __expf(-val));
        if (RES == 1) val += resid[(size_t)m * ldc + n];
        if (OBF == 1)
          ((unsigned short*)Cout)[(size_t)m * ldc + n] = f2bf(val);
        else
          ((float*)Cout)[(size_t)m * ldc + n] = val;
      }
    }
  }
}

// ---------------------------------------------------------------------------
// Fused attention: MFMA QK^T + 3-bin masked softmax + MFMA PV, per (b,h).
// XCD-aware block mapping: resident blocks on each XCD cover 4 batches x 8
// heads so each batch's q/k/v panel is L2-local instead of 8x re-fetched.
__global__ __launch_bounds__(512) void msa_fused(
    const unsigned short* __restrict__ qkvb,
    const unsigned long long* __restrict__ bits,
    float* __restrict__ attn_out, unsigned short* __restrict__ mob) {
  const int blk = blockIdx.x;
  const int b = (blk & 7) * 8 + (blk >> 6);   // bijective on [0,512)
  const int h = (blk >> 3) & 7;
  __shared__ __align__(16) unsigned short Kl[256][72];
  __shared__ __align__(16) unsigned short Vt[64][264];
  __shared__ __align__(16) unsigned short Pl[8][16][264];
  const int tid = threadIdx.x;
  const int wv = tid >> 6, lane = tid & 63;
  const int l15 = lane & 15, fq = lane >> 4;
  // --- stage K ---
  {
    const unsigned short* kgp = qkvb + (size_t)(b * 256) * 1536 + 512 + h * 64;
#pragma unroll
    for (int i = 0; i < 4; ++i) {
      int s = tid + i * 512;
      int row = s >> 3, c8 = (s & 7) << 3;
      *(uint4*)&Kl[row][c8] = *(const uint4*)&kgp[(size_t)row * 1536 + c8];
    }
  }
  // --- stage V transposed ---
  {
    int rv = tid & 255, half = tid >> 8;
    const unsigned short* vgp =
        qkvb + (size_t)(b * 256 + rv) * 1536 + 1024 + h * 64 + half * 32;
#pragma unroll
    for (int j4 = 0; j4 < 4; ++j4) {
      unsigned short tmp[8];
      *(uint4*)tmp = *(const uint4*)&vgp[j4 * 8];
#pragma unroll
      for (int j = 0; j < 8; ++j) Vt[half * 32 + j4 * 8 + j][rv] = tmp[j];
    }
  }
  __syncthreads();
#pragma unroll
  for (int mf = 0; mf < 2; ++mf) {
    const int r0 = wv * 32 + mf * 16;
    const unsigned short* qgp =
        qkvb + (size_t)(b * 256 + r0 + l15) * 1536 + h * 64 + fq * 8;
    bf16x8 aq0 = *(const bf16x8*)qgp;
    bf16x8 aq1 = *(const bf16x8*)(qgp + 32);
    f32x4 accs[16];
#pragma unroll
    for (int nt = 0; nt < 16; ++nt) {
      bf16x8 bk0 = *(const bf16x8*)&Kl[nt * 16 + l15][fq * 8];
      bf16x8 bk1 = *(const bf16x8*)&Kl[nt * 16 + l15][32 + fq * 8];
      f32x4 a = {};
      a = __builtin_amdgcn_mfma_f32_16x16x32_bf16(aq0, bk0, a, 0, 0, 0);
      a = __builtin_amdgcn_mfma_f32_16x16x32_bf16(aq1, bk1, a, 0, 0, 0);
      accs[nt] = a;
    }
#pragma unroll
    for (int bin = 0; bin < 3; ++bin) {
      float* pbase = attn_out + ((size_t)((bin * 64 + b) * 8 + h)) * 65536;
#pragma unroll
      for (int r = 0; r < 4; ++r) {
        const int row = r0 + fq * 4 + r;
        const unsigned long long* bw =
            bits + (size_t)(b * 256 + row) * 12 + bin * 4;
        const unsigned long long w0 = bw[0], w1 = bw[1], w2 = bw[2], w3 = bw[3];
        float p[16];
        float m = -3e38f;
#pragma unroll
        for (int nt = 0; nt < 16; ++nt) {
          unsigned long long w = (nt < 4) ? w0 : (nt < 8) ? w1 : (nt < 12) ? w2 : w3;
          unsigned keep = (unsigned)(w >> ((nt & 3) * 16 + l15)) & 1u;
          float sv = accs[nt][r] * 0.125f;
          p[nt] = keep ? sv : NEGV;
          m = fmaxf(m, p[nt]);
        }
        m = fmaxf(m, __shfl_xor(m, 1));
        m = fmaxf(m, __shfl_xor(m, 2));
        m = fmaxf(m, __shfl_xor(m, 4));
        m = fmaxf(m, __shfl_xor(m, 8));
        float sum = 0.f;
#pragma unroll
        for (int nt = 0; nt < 16; ++nt) { p[nt] = __expf(p[nt] - m); sum += p[nt]; }
        sum += __shfl_xor(sum, 1);
        sum += __shfl_xor(sum, 2);
        sum += __shfl_xor(sum, 4);
        sum += __shfl_xor(sum, 8);
        const float inv = 1.f / sum;
        float* prow = pbase + (size_t)row * 256 + l15;
#pragma unroll
        for (int nt = 0; nt < 16; ++nt) {
          float val = p[nt] * inv;
          prow[nt * 16] = val;
          Pl[wv][fq * 4 + r][nt * 16 + l15] = f2bf(val);
        }
      }
      asm volatile("s_waitcnt lgkmcnt(0)" ::: "memory");
      f32x4 acco[4] = {};
#pragma unroll
      for (int c = 0; c < 8; ++c) {
        bf16x8 pa = *(const bf16x8*)&Pl[wv][l15][c * 32 + fq * 8];
#pragma unroll
        for (int nf = 0; nf < 4; ++nf) {
          bf16x8 bv = *(const bf16x8*)&Vt[nf * 16 + l15][c * 32 + fq * 8];
          acco[nf] = __builtin_amdgcn_mfma_f32_16x16x32_bf16(pa, bv, acco[nf], 0, 0, 0);
        }
      }
#pragma unroll
      for (int nf = 0; nf < 4; ++nf)
#pragma unroll
        for (int r = 0; r < 4; ++r)
          mob[((size_t)(b * 256 + r0 + fq * 4 + r) * 3 + bin) * 512 +
              h * 64 + nf * 16 + l15] = f2bf(acco[nf][r]);
    }
  }
}

// ---------------------------------------------------------------------------
__global__ __launch_bounds__(256) void msa_ln(const float* __restrict__ h2,
                                              const float* __restrict__ gamma,
                                              const float* __restrict__ beta,
                                              float* __restrict__ outp) {
  const int row = blockIdx.x * 4 + (threadIdx.x >> 6);
  const int lane = threadIdx.x & 63;
  const float* hp = h2 + (size_t)row * 512 + lane * 8;
  float4 v0 = *(const float4*)hp;
  float4 v1 = *(const float4*)(hp + 4);
  float s = v0.x + v0.y + v0.z + v0.w + v1.x + v1.y + v1.z + v1.w;
#pragma unroll
  for (int off = 32; off > 0; off >>= 1) s += __shfl_xor(s, off);
  float mu = s * (1.f / 512.f);
  float d[8] = {v0.x - mu, v0.y - mu, v0.z - mu, v0.w - mu,
                v1.x - mu, v1.y - mu, v1.z - mu, v1.w - mu};
  float sq = 0.f;
#pragma unroll
  for (int j = 0; j < 8; ++j) sq += d[j] * d[j];
#pragma unroll
  for (int off = 32; off > 0; off >>= 1) sq += __shfl_xor(sq, off);
  float inv = 1.f / sqrtf(sq * (1.f / 512.f) + 1e-6f);
  const float* gp = gamma + lane * 8;
  const float* bp = beta + lane * 8;
  float* op = outp + (size_t)row * 512 + lane * 8;
#pragma unroll
  for (int j = 0; j < 8; ++j) op[j] = d[j] * inv * gp[j] + bp[j];
}

// ---------------------------------------------------------------------------
extern "C" void kernel_launch(void* const* d_in, const int* in_sizes, int n_in,
                              void* d_out, int out_size, void* d_ws, size_t ws_size,
                              hipStream_t stream) {
  (void)in_sizes; (void)n_in; (void)out_size; (void)ws_size;
  const float* x        = (const float*)d_in[0];
  const float* dist     = (const float*)d_in[1];
  const float* dist_bar = (const float*)d_in[2];
  const float* mask     = (const float*)d_in[3];
  const float* Wq  = (const float*)d_in[4];  const float* bq  = (const float*)d_in[5];
  const float* Wk  = (const float*)d_in[6];  const float* bk  = (const float*)d_in[7];
  const float* Wv  = (const float*)d_in[8];  const float* bv  = (const float*)d_in[9];
  const float* Wa  = (const float*)d_in[10]; const float* ba  = (const float*)d_in[11];
  const float* Ws1 = (const float*)d_in[12]; const float* bs1 = (const float*)d_in[13];
  const float* Ws2 = (const float*)d_in[14]; const float* bs2 = (const float*)d_in[15];
  const float* gamma = (const float*)d_in[16]; const float* beta = (const float*)d_in[17];

  char* w8 = (char*)d_ws;
  const size_t SZ = 8388608;                         // 16384*512
  unsigned short* qkvb = (unsigned short*)(w8 + 0);            // 50.3 MB [16384][1536]
  unsigned short* mob  = (unsigned short*)(w8 + 50331648);     // 50.3 MB [16384][1536]
  unsigned short* xb   = (unsigned short*)(w8 + 100663296);    // 16.8 MB
  unsigned short* Wqkvb= (unsigned short*)(w8 + 117440512);    // 1.6 MB [1536][512]
  unsigned short* Ws2b = (unsigned short*)(w8 + 119013376);    // 0.5 MB
  unsigned short* Wcatb= (unsigned short*)(w8 + 119537664);    // 1.6 MB [512][1536]
  float* bcomb = (float*)(w8 + 121110528);                     // 2 KB
  float* bqkv  = (float*)(w8 + 121112576);                     // 6 KB
  unsigned long long* bits = (unsigned long long*)(w8 + 121118720);  // 1.6 MB
  unsigned short* h1b = qkvb;                        // qkvb dead after msa_fused
  float* h2 = (float*)(w8 + 16777216);               // fits in qkvb region tail
  float* outp = (float*)d_out;
  float* attn = outp + SZ;                           // [3,B,8,256,256] fp32

  msa_prep<<<13507, 256, 0, stream>>>(x, Wq, Wk, Wv, Ws2, Ws1, Wa, bq, bk, bv,
                                      ba, bs1, dist, dist_bar, mask,
                                      xb, Wqkvb, Ws2b, Wcatb, bcomb, bqkv, bits);

  // qkv = x @ [Wq;Wk;Wv]^T + bqkv   (bf16 out; grid 1536 = 3/CU, keep BK=32)
  msa_gemm_mfma<0, 0, 1, 32><<<dim3(128, 12), 256, 0, stream>>>(
      xb, 512, Wqkvb, 512, bqkv, nullptr, qkvb, 1536, 512);

  msa_fused<<<512, 512, 0, stream>>>(qkvb, bits, attn, mob);

  // h1b = silu(mob @ Wcatb^T + bcomb)   [bf16 out; grid-limited -> BK=64]
  msa_gemm_mfma<1, 0, 1, 64><<<dim3(128, 4), 256, 0, stream>>>(
      mob, 1536, Wcatb, 1536, bcomb, nullptr, h1b, 512, 1536);
  // h2 = h1b @ Ws2b^T + bs2 + x          [fp32 out; grid-limited -> BK=64]
  msa_gemm_mfma<0, 1, 0, 64><<<dim3(128, 4), 256, 0, stream>>>(
      h1b, 512, Ws2b, 512, bs2, x, h2, 512, 512);

  msa_ln<<<4096, 256, 0, stream>>>(h2, gamma, beta, outp);
}